// Round 13
// baseline (1477.656 us; speedup 1.0000x reference)
//
#include <hip/hip_runtime.h>
#include <math.h>

#define BB 512
#define LL 128
#define FD 8
#define HD 512
#define EPSV 1e-5f

typedef __attribute__((ext_vector_type(8))) __bf16 bf16x8;
typedef __attribute__((ext_vector_type(4))) float floatx4;
typedef __attribute__((ext_vector_type(8))) unsigned short us8;

__device__ __forceinline__ float silu_f(float x){ return x / (1.0f + expf(-x)); }
__device__ __forceinline__ float softplus_f(float x){ return (x > 20.0f) ? x : log1pf(expf(x)); }

__device__ __forceinline__ unsigned short f2bf(float x){
    union { float f; unsigned u; } v; v.f = x;
    unsigned r = v.u + 0x7fffu + ((v.u >> 16) & 1u);   // RNE
    return (unsigned short)(r >> 16);
}
__device__ __forceinline__ float bf2f(unsigned short h){
    union { unsigned u; float f; } v; v.u = ((unsigned)h) << 16; return v.f;
}
__device__ __forceinline__ void split_bf(float x, unsigned short* hi, unsigned short* lo){
    unsigned short h = f2bf(x);
    *hi = h;
    *lo = f2bf(x - bf2f(h));
}

// ---------------- embed: h = x @ w0 + b0 -> hi/lo bf16 (residual stream stays split) ----------------
__global__ __launch_bounds__(256) void k_embed(const float* __restrict__ x,
    const float* __restrict__ w0, const float* __restrict__ b0,
    unsigned short* __restrict__ hhi, unsigned short* __restrict__ hlo)
{
    int idx = blockIdx.x*256 + threadIdx.x;      // over rows*HD
    int c = idx & (HD-1);
    int row = idx >> 9;
    const float* xr = x + (size_t)row*FD;
    float acc = b0[c];
    #pragma unroll
    for (int f=0; f<FD; ++f) acc = fmaf(xr[f], w0[f*HD + c], acc);
    unsigned short hi, lo; split_bf(acc, &hi, &lo);
    hhi[idx] = hi; hlo[idx] = lo;
}

// ---------------- weight transpose+split for BOTH layers: W[K][N] -> Wt[N][K] bf16 hi/lo ----------------
// Weights KEEP the split (B-operand uses 2 MFMAs: ah*bh + ah*bl).
__global__ __launch_bounds__(256) void k_cvt2(const float* __restrict__ W0,
    const float* __restrict__ W1,
    unsigned short* __restrict__ Th0, unsigned short* __restrict__ Tl0,
    unsigned short* __restrict__ Th1, unsigned short* __restrict__ Tl1,
    int N, int kbits)
{
    int total = N << kbits;
    int idx = blockIdx.x*256 + threadIdx.x;
    const float* W = W0; unsigned short* Th = Th0; unsigned short* Tl = Tl0;
    if (idx >= total) { idx -= total; W = W1; Th = Th1; Tl = Tl1; }
    int K = 1 << kbits;
    int n = idx >> kbits, k = idx & (K-1);
    float v = W[(size_t)k*N + n];
    unsigned short hi, lo; split_bf(v, &hi, &lo);
    Th[idx] = hi; Tl[idx] = lo;
}

// ---------------- U = xp_w @ dt_w (512x512, B-layout [n][c]) + biasU, both layers ----------------
__global__ __launch_bounds__(256) void k_mkU2(
    const float* __restrict__ xw0, const float* __restrict__ dw0,
    const float* __restrict__ xpb0, const float* __restrict__ dtb0,
    const float* __restrict__ xw1, const float* __restrict__ dw1,
    const float* __restrict__ xpb1, const float* __restrict__ dtb1,
    unsigned short* __restrict__ Uhi0, unsigned short* __restrict__ Ulo0,
    unsigned short* __restrict__ Uhi1, unsigned short* __restrict__ Ulo1,
    float* __restrict__ bU0, float* __restrict__ bU1)
{
    int blk = blockIdx.x, tid = threadIdx.x;
    if (blk < 2048) {
        int layer = blk >> 10;
        const float* xw = layer ? xw1 : xw0;
        const float* dw = layer ? dw1 : dw0;
        unsigned short* Uh = layer ? Uhi1 : Uhi0;
        unsigned short* Ul = layer ? Ulo1 : Ulo0;
        int idx = (blk & 1023)*256 + tid;        // n*512 + c, c fastest
        int n = idx >> 9, c = idx & 511;
        float acc = 0.0f;
        #pragma unroll
        for (int j = 0; j < 16; ++j) acc = fmaf(xw[c*16 + j], dw[j*512 + n], acc);
        unsigned short hi, lo; split_bf(acc, &hi, &lo);
        Uh[idx] = hi; Ul[idx] = lo;
    } else {
        int q = blk - 2048;                      // 0..3
        int layer = q >> 1;
        const float* xpb = layer ? xpb1 : xpb0;
        const float* dw  = layer ? dw1  : dw0;
        const float* dtb = layer ? dtb1 : dtb0;
        float* bU = layer ? bU1 : bU0;
        int n = (q & 1)*256 + tid;
        float acc = dtb[n];
        #pragma unroll
        for (int j = 0; j < 16; ++j) acc = fmaf(xpb[j], dw[j*512 + n], acc);
        bU[n] = acc;
    }
}

// ---------------- bf16-A x split-B MFMA GEMM, 128x128 tile, 8 waves, 16x16x32, BK=64 ----------------
// Round-26 == round-24/25 resubmitted verbatim (both prior attempts died on container
// acquisition — "MI355X container failed twice" — before any kernel signal; the axis-swap
// hypothesis is still untested and the diff vs the known-good round-10 kernel is only the
// grid mapping, which cannot affect container acquisition).
// ONE change vs the round-8 anchor (1417us): GRID AXIS SWAP for cache locality.
// Old: blockIdx.x = M-tile (fast) -> all 256 M-tiles of strip 0 dispatch before strip 1; each
// A-tile's reuse across the 8 N-strips is separated by ~100MB of traffic -> L3 evicts A between
// strips -> FETCH 74.5MB vs ~36MB ideal, and those HBM-miss staging loads (~900cy) lengthen the
// per-K-step vmcnt drain (kernel is latency-bound: Mfma 27 / VALU 40 / HBM 17).
// New: blockIdx.x = N-strip (fast), blockIdx.y = M-tile. 8 consecutive blocks = the 8 strips of
// ONE M-tile, round-robin across the 8 XCDs: A-tile fetched once into die-level L3, hit by the
// other 7 XCDs; B-strip s pins to XCD s -> 2MB weights become L2-resident per XCD.
// Everything else byte-identical to round-8 (VGPR=56, LDS 48KB, XOR swizzle, fused epilogues).
// MODE 0 (in_proj, K=512, N=1024): A=hhi.
//    nBase<512  (z):  silu -> Abig[row][512+col] bf16 (hi only)
//    nBase>=512 (xi): fused conv3+silu -> xc[row][col-512] bf16 (hi only)
// MODE 1 (out_proj, K=1024, N=512): A=Abig; outF = v + bias + resid(hi/lo) fp32
// MODE 2 (dt, K=512, N=512): A=xc; out = xc * softplus(v + biasU) -> Abig[row][col] (hi only)
template<int KDIM, int MODE>
__global__ __launch_bounds__(512, 4) void k_mgemm(
    const unsigned short* __restrict__ Ahi,
    const unsigned short* __restrict__ Bhi, const unsigned short* __restrict__ Blo,
    const float* __restrict__ bias,
    const float* __restrict__ cw, const float* __restrict__ cb,
    const unsigned short* __restrict__ rhi, const unsigned short* __restrict__ rlo,
    float* __restrict__ outF,
    unsigned short* __restrict__ oAhi,
    unsigned short* __restrict__ xchi)
{
    // LDS (ushort elems): A [0,8192) | Bhi [8192,16384) | Blo [16384,24576) = 49152 B.
    // Epilogue reuses first 33280 B as sc[128][65] fp32.
    __shared__ __align__(16) char smem[49152];
    unsigned short* lds = (unsigned short*)smem;
    const int tid  = threadIdx.x;
    const int wv   = tid >> 6, lane = tid & 63;
    const int quad = lane >> 4, l16 = lane & 15;
    const size_t mBase = (size_t)blockIdx.y * 128;   // M slow — 8 strips of one M-tile run together
    const int nBase = blockIdx.x * 128;              // N-strip fast — strip s pins to XCD s
    const int wm = (wv & 3) * 32, wn = (wv >> 2) * 64;

    floatx4 acc[2][4] = {};

    const int rowIn = lane >> 2;                 // 0..15
    const int kofs  = ((lane & 3) ^ ((lane >> 3) & 3)) * 8;  // swizzled source k-chunk
    const int qx    = (quad ^ ((l16 >> 1) & 3)) * 8;         // swizzled read k-chunk
    const unsigned short* gsrc[3];
    gsrc[0] = Ahi + mBase * KDIM;
    gsrc[1] = Bhi + (size_t)nBase * KDIM;
    gsrc[2] = Blo + (size_t)nBase * KDIM;

    for (int k0 = 0; k0 < KDIM; k0 += 64) {
        // stage 3 operand tiles x 2 k-sub-tiles; 6 global_load_lds per thread
        #pragma unroll
        for (int b = 0; b < 3; ++b) {
            #pragma unroll
            for (int s = 0; s < 2; ++s) {
                int row = wv * 16 + rowIn;
                const unsigned short* g = gsrc[b] + (size_t)row * KDIM + k0 + s*32 + kofs;
                unsigned short* l = &lds[b * 8192 + s * 4096 + wv * 512]; // +lane*16B implicit
                __builtin_amdgcn_global_load_lds(
                    (const __attribute__((address_space(1))) void*)g,
                    (__attribute__((address_space(3))) void*)l, 16, 0, 0);
            }
        }
        __syncthreads();
        #pragma unroll
        for (int s = 0; s < 2; ++s) {
            const int kb = s * 4096;
            bf16x8 ah[2];
            #pragma unroll
            for (int i = 0; i < 2; ++i) {
                int am = wm + 16*i + l16;
                ah[i] = *(const bf16x8*)&lds[kb + am*32 + qx];
            }
            #pragma unroll
            for (int j = 0; j < 4; ++j) {
                int bn = wn + 16*j + l16;
                bf16x8 bh = *(const bf16x8*)&lds[ 8192 + kb + bn*32 + qx];
                bf16x8 bl = *(const bf16x8*)&lds[16384 + kb + bn*32 + qx];
                #pragma unroll
                for (int i = 0; i < 2; ++i) {
                    acc[i][j] = __builtin_amdgcn_mfma_f32_16x16x32_bf16(ah[i], bh, acc[i][j], 0, 0, 0);
                    acc[i][j] = __builtin_amdgcn_mfma_f32_16x16x32_bf16(ah[i], bl, acc[i][j], 0, 0, 0);
                }
            }
        }
        __syncthreads();
    }

    // ---- unified coalesced epilogue: two 64-col halves through LDS (stride 65) ----
    float* sc = (float*)smem;
    const int q8 = (tid & 7) * 8;                // col chunk within half
    const int rg = tid >> 3;                     // 0..63 row group
    #pragma unroll
    for (int half = 0; half < 2; ++half) {
        __syncthreads();
        if ((wv >> 2) == half) {                 // 4 waves owning this half stage v+bias
            #pragma unroll
            for (int i = 0; i < 2; ++i)
                #pragma unroll
                for (int r = 0; r < 4; ++r) {
                    int rl = wm + 16*i + quad*4 + r;
                    #pragma unroll
                    for (int j = 0; j < 4; ++j) {
                        int cl = 16*j + l16;
                        sc[rl*65 + cl] = acc[i][j][r] + bias[nBase + half*64 + cl];
                    }
                }
        }
        __syncthreads();
        #pragma unroll
        for (int pss = 0; pss < 2; ++pss) {
            int l = pss*64 + rg;                 // row within 128-row tile
            size_t grow = mBase + l;
            if (MODE == 0) {
                if (nBase < 512) {               // z half: silu -> Abig[:,512+col] (hi only)
                    int gcol = nBase + half*64 + q8;
                    us8 hh;
                    #pragma unroll
                    for (int k = 0; k < 8; ++k)
                        hh[k] = f2bf(silu_f(sc[l*65 + q8 + k]));
                    *(us8*)(oAhi + grow*1024 + 512 + gcol) = hh;
                } else {                         // xi half: conv3+silu -> xc (hi only)
                    int gcol = (nBase - 512) + half*64 + q8;
                    us8 hh;
                    #pragma unroll
                    for (int k = 0; k < 8; ++k) {
                        int cc = q8 + k;
                        float xm = (l > 0)   ? sc[(l-1)*65 + cc] : 0.0f;
                        float x0 = sc[l*65 + cc];
                        float xp = (l < 127) ? sc[(l+1)*65 + cc] : 0.0f;
                        int gc = gcol + k;
                        float v = cb[gc];
                        v = fmaf(xm, cw[gc*3+0], v);
                        v = fmaf(x0, cw[gc*3+1], v);
                        v = fmaf(xp, cw[gc*3+2], v);
                        hh[k] = f2bf(silu_f(v));
                    }
                    *(us8*)(xchi + grow*512 + gcol) = hh;
                }
            } else if (MODE == 1) {              // fp32 out = (v+bias) + resid(hi/lo), float4 x2
                int gcol = nBase + half*64 + q8;
                us8 rh = *(const us8*)(rhi + grow*512 + gcol);
                us8 rl = *(const us8*)(rlo + grow*512 + gcol);
                float o[8];
                #pragma unroll
                for (int k = 0; k < 8; ++k)
                    o[k] = sc[l*65 + q8 + k] + (bf2f(rh[k]) + bf2f(rl[k]));
                float4 o0, o1;
                o0.x=o[0]; o0.y=o[1]; o0.z=o[2]; o0.w=o[3];
                o1.x=o[4]; o1.y=o[5]; o1.z=o[6]; o1.w=o[7];
                *(float4*)(outF + grow*512 + gcol)     = o0;
                *(float4*)(outF + grow*512 + gcol + 4) = o1;
            } else {                             // MODE 2: xid = xc*softplus(v) (hi only out)
                int gcol = nBase + half*64 + q8;
                us8 xh = *(const us8*)(Ahi + grow*512 + gcol);
                us8 hh;
                #pragma unroll
                for (int k = 0; k < 8; ++k) {
                    float o = bf2f(xh[k]) * softplus_f(sc[l*65 + q8 + k]);
                    hh[k] = f2bf(o);
                }
                *(us8*)(oAhi + grow*1024 + gcol) = hh;
            }
        }
    }
}

// ---------------- layernorm of pre-summed row (resid already added in MODE1 epilogue) ----------------
// Emits hi/lo bf16 + per-block (4-row) channel partials -> regp2; k_head sums 32 partials/batch.
__global__ __launch_bounds__(256) void k_ln(const float* __restrict__ in,
    const float* __restrict__ g, const float* __restrict__ b,
    unsigned short* ohi, unsigned short* olo, float* __restrict__ regp2)
{
    __shared__ float sacc[4][512];
    int wv = threadIdx.x >> 6, lane = threadIdx.x & 63;
    size_t row = (size_t)blockIdx.x * 4 + wv;
    size_t base = row*512 + lane*8;
    float4 v0 = *(const float4*)(in + base);
    float4 v1 = *(const float4*)(in + base + 4);
    float vals[8] = {v0.x,v0.y,v0.z,v0.w,v1.x,v1.y,v1.z,v1.w};
    float s = 0.f, q = 0.f;
    #pragma unroll
    for (int k = 0; k < 8; ++k) { s += vals[k]; q += vals[k]*vals[k]; }
    #pragma unroll
    for (int off = 32; off; off >>= 1) { s += __shfl_xor(s, off); q += __shfl_xor(q, off); }
    float mu = s * (1.0f/512.0f);
    float rs = rsqrtf(q*(1.0f/512.0f) - mu*mu + EPSV);
    const float* gp = g + lane*8;
    const float* bp = b + lane*8;
    float4 g0 = *(const float4*)gp, g1 = *(const float4*)(gp+4);
    float4 b0 = *(const float4*)bp, b1 = *(const float4*)(bp+4);
    float gs[8] = {g0.x,g0.y,g0.z,g0.w,g1.x,g1.y,g1.z,g1.w};
    float bs[8] = {b0.x,b0.y,b0.z,b0.w,b1.x,b1.y,b1.z,b1.w};
    us8 hh, ll;
    #pragma unroll
    for (int k = 0; k < 8; ++k) {
        float o = (vals[k] - mu) * rs * gs[k] + bs[k];
        sacc[wv][lane*8 + k] = o;
        unsigned short hi, lo; split_bf(o, &hi, &lo);
        hh[k] = hi; ll[k] = lo;
    }
    *(us8*)(ohi + base) = hh;
    *(us8*)(olo + base) = ll;
    __syncthreads();
    int ch = threadIdx.x * 2;
    float s0 = (sacc[0][ch]   + sacc[1][ch])   + (sacc[2][ch]   + sacc[3][ch]);
    float s1 = (sacc[0][ch+1] + sacc[1][ch+1]) + (sacc[2][ch+1] + sacc[3][ch+1]);
    float2 o2; o2.x = s0; o2.y = s1;
    *(float2*)(regp2 + (size_t)blockIdx.x*512 + ch) = o2;
}

// ---------------- head: reg from k_ln partials; gate softmax+argmax; expert select ----------------
__global__ __launch_bounds__(512) void k_head(
    const unsigned short* __restrict__ hhi, const unsigned short* __restrict__ hlo,
    const float* __restrict__ regp2,
    const float* __restrict__ gumbel, const float* __restrict__ gate_w,
    const float* __restrict__ gate_b, const float* __restrict__ actor_w,
    const float* __restrict__ actor_b, const float* __restrict__ critic_w,
    const float* __restrict__ critic_b, float* __restrict__ out, int bofs)
{
    __shared__ float sred[8][4];
    __shared__ float sg;
    __shared__ int sestar;
    int bl = blockIdx.x, tid = threadIdx.x;      // tid = channel
    int b = bofs + bl;
    size_t base = (size_t)bl * LL * HD;
    const float* rp = regp2 + (size_t)bl*32*512; // 32 partial blocks per batch (128 rows / 4)
    float r0 = 0.0f;
    #pragma unroll
    for (int p = 0; p < 32; ++p) r0 += rp[p*512 + tid];
    r0 *= (1.0f/LL);
    size_t od = base + (LL-1)*HD + tid;
    float dec0 = bf2f(hhi[od]) + bf2f(hlo[od]);

    int lane = tid & 63, wid = tid >> 6;
    float p[4];
    #pragma unroll
    for (int e = 0; e < 4; ++e) p[e] = r0 * gate_w[tid*4 + e];
    #pragma unroll
    for (int e = 0; e < 4; ++e) {
        float v = p[e];
        for (int off = 32; off; off >>= 1) v += __shfl_down(v, off);
        p[e] = v;
    }
    if (!lane) { for (int e = 0; e < 4; ++e) sred[wid][e] = p[e]; }
    __syncthreads();
    if (!tid) {
        float ge[4]; float mx = -1e30f;
        for (int e = 0; e < 4; ++e) {
            float acc = gate_b[e] + gumbel[b*4 + e];
            for (int w = 0; w < 8; ++w) acc += sred[w][e];
            ge[e] = acc;
            if (acc > mx) mx = acc;
        }
        float ys[4], den = 0.f;
        for (int e = 0; e < 4; ++e) { ys[e] = expf(ge[e] - mx); den += ys[e]; }
        int estar = 0; float best = ge[0];
        for (int e = 1; e < 4; ++e) if (ge[e] > best) { best = ge[e]; estar = e; }
        float ye = ys[estar] / den;
        float gv = (1.0f + ye) - ye;             // exactly as reference
        for (int e = 0; e < 4; ++e) out[2048 + b*4 + e] = (e == estar) ? gv : 0.0f;
        sg = gv; sestar = estar;
    }
    __syncthreads();
    float gv = sg; int estar = sestar;
    const float* aw  = actor_w  + (size_t)estar * HD * 3;
    const float* cwp = critic_w + (size_t)estar * HD;
    float q[4];
    #pragma unroll
    for (int a = 0; a < 3; ++a) q[a] = dec0 * aw[tid*3 + a];
    q[3] = dec0 * cwp[tid];
    #pragma unroll
    for (int e = 0; e < 4; ++e) {
        float v = q[e];
        for (int off = 32; off; off >>= 1) v += __shfl_down(v, off);
        q[e] = v;
    }
    __syncthreads();
    if (!lane) { for (int e = 0; e < 4; ++e) sred[wid][e] = q[e]; }
    __syncthreads();
    if (!tid) {
        for (int a = 0; a < 3; ++a) {
            float acc = actor_b[estar*3 + a];
            for (int w = 0; w < 8; ++w) acc += sred[w][a];
            out[b*3 + a] = gv * acc;
        }
        float acc = critic_b[estar];
        for (int w = 0; w < 8; ++w) acc += sred[w][3];
        out[1536 + b] = gv * acc;
    }
}

extern "C" void kernel_launch(void* const* d_in, const int* in_sizes, int n_in,
                              void* d_out, int out_size, void* d_ws, size_t ws_size,
                              hipStream_t stream)
{
    const float* x        = (const float*)d_in[0];
    const float* gumbel   = (const float*)d_in[1];
    const float* w0       = (const float*)d_in[2];
    const float* b0       = (const float*)d_in[3];
    const float* ln_g     = (const float*)d_in[4];
    const float* ln_b     = (const float*)d_in[5];
    const float* gate_w   = (const float*)d_in[6];
    const float* gate_b   = (const float*)d_in[7];
    const float* actor_w  = (const float*)d_in[8];
    const float* actor_b  = (const float*)d_in[9];
    const float* critic_w = (const float*)d_in[10];
    const float* critic_b = (const float*)d_in[11];
    const float* in_w[2]   = {(const float*)d_in[12], (const float*)d_in[22]};
    const float* in_b[2]   = {(const float*)d_in[13], (const float*)d_in[23]};
    const float* conv_w[2] = {(const float*)d_in[14], (const float*)d_in[24]};
    const float* conv_b[2] = {(const float*)d_in[15], (const float*)d_in[25]};
    const float* xp_w[2]   = {(const float*)d_in[16], (const float*)d_in[26]};
    const float* xp_b[2]   = {(const float*)d_in[17], (const float*)d_in[27]};
    const float* dt_w[2]   = {(const float*)d_in[18], (const float*)d_in[28]};
    const float* dt_b[2]   = {(const float*)d_in[19], (const float*)d_in[29]};
    const float* out_w[2]  = {(const float*)d_in[20], (const float*)d_in[30]};
    const float* out_b[2]  = {(const float*)d_in[21], (const float*)d_in[31]};

    // Per-row scratch: union(xb fp32 | xchi)(2048) + hhi/hlo(2048) + Abig hi(2048) = 6144 B
    int CB = 512;
    while (CB > 1 && (size_t)CB * LL * 6144 + (16u << 20) > ws_size) CB >>= 1;
    const int rows = CB * LL;
    const size_t CSZ = (size_t)rows * HD;        // elements per 512-wide buffer

    char* p = (char*)d_ws;
    float* xb = (float*)p;                       // union with xchi (phases don't overlap)
    unsigned short* xchi = (unsigned short*)p;   p += CSZ * 4;
    unsigned short* hhi = (unsigned short*)p;    p += CSZ * 2;
    unsigned short* hlo = (unsigned short*)p;    p += CSZ * 2;
    unsigned short* Abig_hi = (unsigned short*)p; p += CSZ * 2 * 2;  // rows x 1024 bf16
    unsigned short* wtb = (unsigned short*)p;  p += (size_t)8 * 524288 * 2;
    unsigned short* iwh[2] = {wtb,            wtb + 4*524288};
    unsigned short* iwl[2] = {wtb +   524288, wtb + 5*524288};
    unsigned short* owh[2] = {wtb + 2*524288, wtb + 6*524288};
    unsigned short* owl[2] = {wtb + 3*524288, wtb + 7*524288};
    unsigned short* Uhi[2] = {(unsigned short*)p, (unsigned short*)p + 262144}; p += 262144u * 2 * 2;
    unsigned short* Ulo[2] = {(unsigned short*)p, (unsigned short*)p + 262144}; p += 262144u * 2 * 2;
    float* biasU[2] = {(float*)p, (float*)p + 512};           p += 1024 * 4;
    // regp2: (rows/4) x 512 fp32 — OVERLAYS Abig_hi (dead after MODE1; k_ln writes it after
    // MODE1 reads Abig; m=1's write is the one k_head consumes; all kernels serial on stream).
    float* regp2 = (float*)Abig_hi;

    // weight transforms: 3 launches
    k_cvt2<<<4096, 256, 0, stream>>>(in_w[0], in_w[1], iwh[0], iwl[0], iwh[1], iwl[1], 1024, 9);
    k_cvt2<<<4096, 256, 0, stream>>>(out_w[0], out_w[1], owh[0], owl[0], owh[1], owl[1], 512, 10);
    k_mkU2<<<2052, 256, 0, stream>>>(xp_w[0], dt_w[0], xp_b[0], dt_b[0],
                                     xp_w[1], dt_w[1], xp_b[1], dt_b[1],
                                     Uhi[0], Ulo[0], Uhi[1], Ulo[1], biasU[0], biasU[1]);

    const int nchunk = BB / CB;
    for (int c = 0; c < nchunk; ++c) {
        const float* xin = x + (size_t)c * CB * LL * FD;
        k_embed<<<rows*HD/256, 256, 0, stream>>>(xin, w0, b0, hhi, hlo);
        for (int m = 0; m < 2; ++m) {
            // in_proj + fused conv: A=hhi; z->Abig[:,512:] (hi), conv(xi)->xc (hi)
            // grid: N-strip FAST (8 strips -> 8 XCDs), M-tile slow
            k_mgemm<512, 0><<<dim3(8, rows/128), 512, 0, stream>>>(
                hhi, iwh[m], iwl[m], in_b[m], conv_w[m], conv_b[m],
                nullptr, nullptr,
                nullptr, Abig_hi, xchi);
            // dt GEMM: A=xc; out = xc * softplus(xc@U + biasU) -> Abig[:,0:512] (hi)
            k_mgemm<512, 2><<<dim3(4, rows/128), 512, 0, stream>>>(
                xchi, Uhi[m], Ulo[m], biasU[m], nullptr, nullptr,
                nullptr, nullptr,
                nullptr, Abig_hi, nullptr);
            // out_proj: A=Abig; out = Abig@out_w + out_b + resid(hhi/hlo) -> xb fp32
            k_mgemm<1024, 1><<<dim3(4, rows/128), 512, 0, stream>>>(
                Abig_hi, owh[m], owl[m], out_b[m], nullptr, nullptr,
                hhi, hlo,
                xb, nullptr, nullptr);
            // LN(xb) -> hhi/hlo + per-4-row channel partials
            k_ln<<<rows/4, 256, 0, stream>>>(xb, ln_g, ln_b, hhi, hlo, regp2);
        }
        k_head<<<CB, 512, 0, stream>>>(hhi, hlo, regp2, gumbel, gate_w, gate_b,
                                       actor_w, actor_b, critic_w, critic_b,
                                       (float*)d_out, c*CB);
    }
}

// Round 14
// 1353.162 us; speedup vs baseline: 1.0920x; 1.0920x over previous
//
#include <hip/hip_runtime.h>
#include <math.h>

#define BB 512
#define LL 128
#define FD 8
#define HD 512
#define EPSV 1e-5f

typedef __attribute__((ext_vector_type(8))) __bf16 bf16x8;
typedef __attribute__((ext_vector_type(4))) float floatx4;
typedef __attribute__((ext_vector_type(8))) unsigned short us8;

__device__ __forceinline__ float silu_f(float x){ return x / (1.0f + expf(-x)); }
__device__ __forceinline__ float softplus_f(float x){ return (x > 20.0f) ? x : log1pf(expf(x)); }

__device__ __forceinline__ unsigned short f2bf(float x){
    union { float f; unsigned u; } v; v.f = x;
    unsigned r = v.u + 0x7fffu + ((v.u >> 16) & 1u);   // RNE
    return (unsigned short)(r >> 16);
}
__device__ __forceinline__ float bf2f(unsigned short h){
    union { unsigned u; float f; } v; v.u = ((unsigned)h) << 16; return v.f;
}
__device__ __forceinline__ void split_bf(float x, unsigned short* hi, unsigned short* lo){
    unsigned short h = f2bf(x);
    *hi = h;
    *lo = f2bf(x - bf2f(h));
}

// ---------------- embed: h = x @ w0 + b0 -> hi/lo bf16 (residual stream stays split) ----------------
__global__ __launch_bounds__(256) void k_embed(const float* __restrict__ x,
    const float* __restrict__ w0, const float* __restrict__ b0,
    unsigned short* __restrict__ hhi, unsigned short* __restrict__ hlo)
{
    int idx = blockIdx.x*256 + threadIdx.x;      // over rows*HD
    int c = idx & (HD-1);
    int row = idx >> 9;
    const float* xr = x + (size_t)row*FD;
    float acc = b0[c];
    #pragma unroll
    for (int f=0; f<FD; ++f) acc = fmaf(xr[f], w0[f*HD + c], acc);
    unsigned short hi, lo; split_bf(acc, &hi, &lo);
    hhi[idx] = hi; hlo[idx] = lo;
}

// ---------------- weight transpose+split for BOTH layers: W[K][N] -> Wt[N][K] bf16 hi/lo ----------------
// Weights KEEP the split (B-operand uses 2 MFMAs: ah*bh + ah*bl).
__global__ __launch_bounds__(256) void k_cvt2(const float* __restrict__ W0,
    const float* __restrict__ W1,
    unsigned short* __restrict__ Th0, unsigned short* __restrict__ Tl0,
    unsigned short* __restrict__ Th1, unsigned short* __restrict__ Tl1,
    int N, int kbits)
{
    int total = N << kbits;
    int idx = blockIdx.x*256 + threadIdx.x;
    const float* W = W0; unsigned short* Th = Th0; unsigned short* Tl = Tl0;
    if (idx >= total) { idx -= total; W = W1; Th = Th1; Tl = Tl1; }
    int K = 1 << kbits;
    int n = idx >> kbits, k = idx & (K-1);
    float v = W[(size_t)k*N + n];
    unsigned short hi, lo; split_bf(v, &hi, &lo);
    Th[idx] = hi; Tl[idx] = lo;
}

// ---------------- U = xp_w @ dt_w (512x512, B-layout [n][c]) + biasU, both layers ----------------
__global__ __launch_bounds__(256) void k_mkU2(
    const float* __restrict__ xw0, const float* __restrict__ dw0,
    const float* __restrict__ xpb0, const float* __restrict__ dtb0,
    const float* __restrict__ xw1, const float* __restrict__ dw1,
    const float* __restrict__ xpb1, const float* __restrict__ dtb1,
    unsigned short* __restrict__ Uhi0, unsigned short* __restrict__ Ulo0,
    unsigned short* __restrict__ Uhi1, unsigned short* __restrict__ Ulo1,
    float* __restrict__ bU0, float* __restrict__ bU1)
{
    int blk = blockIdx.x, tid = threadIdx.x;
    if (blk < 2048) {
        int layer = blk >> 10;
        const float* xw = layer ? xw1 : xw0;
        const float* dw = layer ? dw1 : dw0;
        unsigned short* Uh = layer ? Uhi1 : Uhi0;
        unsigned short* Ul = layer ? Ulo1 : Ulo0;
        int idx = (blk & 1023)*256 + tid;        // n*512 + c, c fastest
        int n = idx >> 9, c = idx & 511;
        float acc = 0.0f;
        #pragma unroll
        for (int j = 0; j < 16; ++j) acc = fmaf(xw[c*16 + j], dw[j*512 + n], acc);
        unsigned short hi, lo; split_bf(acc, &hi, &lo);
        Uh[idx] = hi; Ul[idx] = lo;
    } else {
        int q = blk - 2048;                      // 0..3
        int layer = q >> 1;
        const float* xpb = layer ? xpb1 : xpb0;
        const float* dw  = layer ? dw1  : dw0;
        const float* dtb = layer ? dtb1 : dtb0;
        float* bU = layer ? bU1 : bU0;
        int n = (q & 1)*256 + tid;
        float acc = dtb[n];
        #pragma unroll
        for (int j = 0; j < 16; ++j) acc = fmaf(xpb[j], dw[j*512 + n], acc);
        bU[n] = acc;
    }
}

// ---------------- bf16-A x split-B MFMA GEMM, 128x128 tile, 8 waves, 16x16x32, BK=64 ----------------
// Round-27: REVERT the axis swap — falsified by counters (FETCH 74.5 -> 135MB, dur 107 -> 118us).
// Mechanism learned: block id = m + 256*n pins M-tile m to XCD m%8, so an A-tile's 8 reuses
// (one per N-strip) hit the SAME XCD's L2; the swapped order made every A-tile fill 8 separate
// per-XCD L2s (L2s not shared). The original M-fast order is the locality-correct one.
// This source == round-8/10 anchor exactly (measured best: 1417us total, absmax 0.0156).
// Structure: bf16-A x split-B (2 MFMAs), XOR chunk swizzle (conflicts 7.86M -> 1.57M/tile-work),
// fused conv/silu/softplus/resid epilogues, k_ln partials (k_rsum deleted), MODE1-resid fusion.
// Known plateau: Mfma 27 / VALU 40 / HBM 17 — 2-barrier-loop latency-bound; pipeline variants
// (rounds 1/4), occupancy bump (9), rank-16 dt (5), axis swap (13) all falsified and reverted.
// MODE 0 (in_proj, K=512, N=1024): A=hhi.
//    nBase<512  (z):  silu -> Abig[row][512+col] bf16 (hi only)
//    nBase>=512 (xi): fused conv3+silu -> xc[row][col-512] bf16 (hi only)
// MODE 1 (out_proj, K=1024, N=512): A=Abig; outF = v + bias + resid(hi/lo) fp32
// MODE 2 (dt, K=512, N=512): A=xc; out = xc * softplus(v + biasU) -> Abig[row][col] (hi only)
template<int KDIM, int MODE>
__global__ __launch_bounds__(512, 4) void k_mgemm(
    const unsigned short* __restrict__ Ahi,
    const unsigned short* __restrict__ Bhi, const unsigned short* __restrict__ Blo,
    const float* __restrict__ bias,
    const float* __restrict__ cw, const float* __restrict__ cb,
    const unsigned short* __restrict__ rhi, const unsigned short* __restrict__ rlo,
    float* __restrict__ outF,
    unsigned short* __restrict__ oAhi,
    unsigned short* __restrict__ xchi)
{
    // LDS (ushort elems): A [0,8192) | Bhi [8192,16384) | Blo [16384,24576) = 49152 B.
    // Epilogue reuses first 33280 B as sc[128][65] fp32.
    __shared__ __align__(16) char smem[49152];
    unsigned short* lds = (unsigned short*)smem;
    const int tid  = threadIdx.x;
    const int wv   = tid >> 6, lane = tid & 63;
    const int quad = lane >> 4, l16 = lane & 15;
    const size_t mBase = (size_t)blockIdx.x * 128;   // M fast — M-tile m pins to XCD m%8; A reuse stays on-XCD
    const int nBase = blockIdx.y * 128;
    const int wm = (wv & 3) * 32, wn = (wv >> 2) * 64;

    floatx4 acc[2][4] = {};

    const int rowIn = lane >> 2;                 // 0..15
    const int kofs  = ((lane & 3) ^ ((lane >> 3) & 3)) * 8;  // swizzled source k-chunk
    const int qx    = (quad ^ ((l16 >> 1) & 3)) * 8;         // swizzled read k-chunk
    const unsigned short* gsrc[3];
    gsrc[0] = Ahi + mBase * KDIM;
    gsrc[1] = Bhi + (size_t)nBase * KDIM;
    gsrc[2] = Blo + (size_t)nBase * KDIM;

    for (int k0 = 0; k0 < KDIM; k0 += 64) {
        // stage 3 operand tiles x 2 k-sub-tiles; 6 global_load_lds per thread
        #pragma unroll
        for (int b = 0; b < 3; ++b) {
            #pragma unroll
            for (int s = 0; s < 2; ++s) {
                int row = wv * 16 + rowIn;
                const unsigned short* g = gsrc[b] + (size_t)row * KDIM + k0 + s*32 + kofs;
                unsigned short* l = &lds[b * 8192 + s * 4096 + wv * 512]; // +lane*16B implicit
                __builtin_amdgcn_global_load_lds(
                    (const __attribute__((address_space(1))) void*)g,
                    (__attribute__((address_space(3))) void*)l, 16, 0, 0);
            }
        }
        __syncthreads();
        #pragma unroll
        for (int s = 0; s < 2; ++s) {
            const int kb = s * 4096;
            bf16x8 ah[2];
            #pragma unroll
            for (int i = 0; i < 2; ++i) {
                int am = wm + 16*i + l16;
                ah[i] = *(const bf16x8*)&lds[kb + am*32 + qx];
            }
            #pragma unroll
            for (int j = 0; j < 4; ++j) {
                int bn = wn + 16*j + l16;
                bf16x8 bh = *(const bf16x8*)&lds[ 8192 + kb + bn*32 + qx];
                bf16x8 bl = *(const bf16x8*)&lds[16384 + kb + bn*32 + qx];
                #pragma unroll
                for (int i = 0; i < 2; ++i) {
                    acc[i][j] = __builtin_amdgcn_mfma_f32_16x16x32_bf16(ah[i], bh, acc[i][j], 0, 0, 0);
                    acc[i][j] = __builtin_amdgcn_mfma_f32_16x16x32_bf16(ah[i], bl, acc[i][j], 0, 0, 0);
                }
            }
        }
        __syncthreads();
    }

    // ---- unified coalesced epilogue: two 64-col halves through LDS (stride 65) ----
    float* sc = (float*)smem;
    const int q8 = (tid & 7) * 8;                // col chunk within half
    const int rg = tid >> 3;                     // 0..63 row group
    #pragma unroll
    for (int half = 0; half < 2; ++half) {
        __syncthreads();
        if ((wv >> 2) == half) {                 // 4 waves owning this half stage v+bias
            #pragma unroll
            for (int i = 0; i < 2; ++i)
                #pragma unroll
                for (int r = 0; r < 4; ++r) {
                    int rl = wm + 16*i + quad*4 + r;
                    #pragma unroll
                    for (int j = 0; j < 4; ++j) {
                        int cl = 16*j + l16;
                        sc[rl*65 + cl] = acc[i][j][r] + bias[nBase + half*64 + cl];
                    }
                }
        }
        __syncthreads();
        #pragma unroll
        for (int pss = 0; pss < 2; ++pss) {
            int l = pss*64 + rg;                 // row within 128-row tile
            size_t grow = mBase + l;
            if (MODE == 0) {
                if (nBase < 512) {               // z half: silu -> Abig[:,512+col] (hi only)
                    int gcol = nBase + half*64 + q8;
                    us8 hh;
                    #pragma unroll
                    for (int k = 0; k < 8; ++k)
                        hh[k] = f2bf(silu_f(sc[l*65 + q8 + k]));
                    *(us8*)(oAhi + grow*1024 + 512 + gcol) = hh;
                } else {                         // xi half: conv3+silu -> xc (hi only)
                    int gcol = (nBase - 512) + half*64 + q8;
                    us8 hh;
                    #pragma unroll
                    for (int k = 0; k < 8; ++k) {
                        int cc = q8 + k;
                        float xm = (l > 0)   ? sc[(l-1)*65 + cc] : 0.0f;
                        float x0 = sc[l*65 + cc];
                        float xp = (l < 127) ? sc[(l+1)*65 + cc] : 0.0f;
                        int gc = gcol + k;
                        float v = cb[gc];
                        v = fmaf(xm, cw[gc*3+0], v);
                        v = fmaf(x0, cw[gc*3+1], v);
                        v = fmaf(xp, cw[gc*3+2], v);
                        hh[k] = f2bf(silu_f(v));
                    }
                    *(us8*)(xchi + grow*512 + gcol) = hh;
                }
            } else if (MODE == 1) {              // fp32 out = (v+bias) + resid(hi/lo), float4 x2
                int gcol = nBase + half*64 + q8;
                us8 rh = *(const us8*)(rhi + grow*512 + gcol);
                us8 rl = *(const us8*)(rlo + grow*512 + gcol);
                float o[8];
                #pragma unroll
                for (int k = 0; k < 8; ++k)
                    o[k] = sc[l*65 + q8 + k] + (bf2f(rh[k]) + bf2f(rl[k]));
                float4 o0, o1;
                o0.x=o[0]; o0.y=o[1]; o0.z=o[2]; o0.w=o[3];
                o1.x=o[4]; o1.y=o[5]; o1.z=o[6]; o1.w=o[7];
                *(float4*)(outF + grow*512 + gcol)     = o0;
                *(float4*)(outF + grow*512 + gcol + 4) = o1;
            } else {                             // MODE 2: xid = xc*softplus(v) (hi only out)
                int gcol = nBase + half*64 + q8;
                us8 xh = *(const us8*)(Ahi + grow*512 + gcol);
                us8 hh;
                #pragma unroll
                for (int k = 0; k < 8; ++k) {
                    float o = bf2f(xh[k]) * softplus_f(sc[l*65 + q8 + k]);
                    hh[k] = f2bf(o);
                }
                *(us8*)(oAhi + grow*1024 + gcol) = hh;
            }
        }
    }
}

// ---------------- layernorm of pre-summed row (resid already added in MODE1 epilogue) ----------------
// Emits hi/lo bf16 + per-block (4-row) channel partials -> regp2; k_head sums 32 partials/batch.
__global__ __launch_bounds__(256) void k_ln(const float* __restrict__ in,
    const float* __restrict__ g, const float* __restrict__ b,
    unsigned short* ohi, unsigned short* olo, float* __restrict__ regp2)
{
    __shared__ float sacc[4][512];
    int wv = threadIdx.x >> 6, lane = threadIdx.x & 63;
    size_t row = (size_t)blockIdx.x * 4 + wv;
    size_t base = row*512 + lane*8;
    float4 v0 = *(const float4*)(in + base);
    float4 v1 = *(const float4*)(in + base + 4);
    float vals[8] = {v0.x,v0.y,v0.z,v0.w,v1.x,v1.y,v1.z,v1.w};
    float s = 0.f, q = 0.f;
    #pragma unroll
    for (int k = 0; k < 8; ++k) { s += vals[k]; q += vals[k]*vals[k]; }
    #pragma unroll
    for (int off = 32; off; off >>= 1) { s += __shfl_xor(s, off); q += __shfl_xor(q, off); }
    float mu = s * (1.0f/512.0f);
    float rs = rsqrtf(q*(1.0f/512.0f) - mu*mu + EPSV);
    const float* gp = g + lane*8;
    const float* bp = b + lane*8;
    float4 g0 = *(const float4*)gp, g1 = *(const float4*)(gp+4);
    float4 b0 = *(const float4*)bp, b1 = *(const float4*)(bp+4);
    float gs[8] = {g0.x,g0.y,g0.z,g0.w,g1.x,g1.y,g1.z,g1.w};
    float bs[8] = {b0.x,b0.y,b0.z,b0.w,b1.x,b1.y,b1.z,b1.w};
    us8 hh, ll;
    #pragma unroll
    for (int k = 0; k < 8; ++k) {
        float o = (vals[k] - mu) * rs * gs[k] + bs[k];
        sacc[wv][lane*8 + k] = o;
        unsigned short hi, lo; split_bf(o, &hi, &lo);
        hh[k] = hi; ll[k] = lo;
    }
    *(us8*)(ohi + base) = hh;
    *(us8*)(olo + base) = ll;
    __syncthreads();
    int ch = threadIdx.x * 2;
    float s0 = (sacc[0][ch]   + sacc[1][ch])   + (sacc[2][ch]   + sacc[3][ch]);
    float s1 = (sacc[0][ch+1] + sacc[1][ch+1]) + (sacc[2][ch+1] + sacc[3][ch+1]);
    float2 o2; o2.x = s0; o2.y = s1;
    *(float2*)(regp2 + (size_t)blockIdx.x*512 + ch) = o2;
}

// ---------------- head: reg from k_ln partials; gate softmax+argmax; expert select ----------------
__global__ __launch_bounds__(512) void k_head(
    const unsigned short* __restrict__ hhi, const unsigned short* __restrict__ hlo,
    const float* __restrict__ regp2,
    const float* __restrict__ gumbel, const float* __restrict__ gate_w,
    const float* __restrict__ gate_b, const float* __restrict__ actor_w,
    const float* __restrict__ actor_b, const float* __restrict__ critic_w,
    const float* __restrict__ critic_b, float* __restrict__ out, int bofs)
{
    __shared__ float sred[8][4];
    __shared__ float sg;
    __shared__ int sestar;
    int bl = blockIdx.x, tid = threadIdx.x;      // tid = channel
    int b = bofs + bl;
    size_t base = (size_t)bl * LL * HD;
    const float* rp = regp2 + (size_t)bl*32*512; // 32 partial blocks per batch (128 rows / 4)
    float r0 = 0.0f;
    #pragma unroll
    for (int p = 0; p < 32; ++p) r0 += rp[p*512 + tid];
    r0 *= (1.0f/LL);
    size_t od = base + (LL-1)*HD + tid;
    float dec0 = bf2f(hhi[od]) + bf2f(hlo[od]);

    int lane = tid & 63, wid = tid >> 6;
    float p[4];
    #pragma unroll
    for (int e = 0; e < 4; ++e) p[e] = r0 * gate_w[tid*4 + e];
    #pragma unroll
    for (int e = 0; e < 4; ++e) {
        float v = p[e];
        for (int off = 32; off; off >>= 1) v += __shfl_down(v, off);
        p[e] = v;
    }
    if (!lane) { for (int e = 0; e < 4; ++e) sred[wid][e] = p[e]; }
    __syncthreads();
    if (!tid) {
        float ge[4]; float mx = -1e30f;
        for (int e = 0; e < 4; ++e) {
            float acc = gate_b[e] + gumbel[b*4 + e];
            for (int w = 0; w < 8; ++w) acc += sred[w][e];
            ge[e] = acc;
            if (acc > mx) mx = acc;
        }
        float ys[4], den = 0.f;
        for (int e = 0; e < 4; ++e) { ys[e] = expf(ge[e] - mx); den += ys[e]; }
        int estar = 0; float best = ge[0];
        for (int e = 1; e < 4; ++e) if (ge[e] > best) { best = ge[e]; estar = e; }
        float ye = ys[estar] / den;
        float gv = (1.0f + ye) - ye;             // exactly as reference
        for (int e = 0; e < 4; ++e) out[2048 + b*4 + e] = (e == estar) ? gv : 0.0f;
        sg = gv; sestar = estar;
    }
    __syncthreads();
    float gv = sg; int estar = sestar;
    const float* aw  = actor_w  + (size_t)estar * HD * 3;
    const float* cwp = critic_w + (size_t)estar * HD;
    float q[4];
    #pragma unroll
    for (int a = 0; a < 3; ++a) q[a] = dec0 * aw[tid*3 + a];
    q[3] = dec0 * cwp[tid];
    #pragma unroll
    for (int e = 0; e < 4; ++e) {
        float v = q[e];
        for (int off = 32; off; off >>= 1) v += __shfl_down(v, off);
        q[e] = v;
    }
    __syncthreads();
    if (!lane) { for (int e = 0; e < 4; ++e) sred[wid][e] = q[e]; }
    __syncthreads();
    if (!tid) {
        for (int a = 0; a < 3; ++a) {
            float acc = actor_b[estar*3 + a];
            for (int w = 0; w < 8; ++w) acc += sred[w][a];
            out[b*3 + a] = gv * acc;
        }
        float acc = critic_b[estar];
        for (int w = 0; w < 8; ++w) acc += sred[w][3];
        out[1536 + b] = gv * acc;
    }
}

extern "C" void kernel_launch(void* const* d_in, const int* in_sizes, int n_in,
                              void* d_out, int out_size, void* d_ws, size_t ws_size,
                              hipStream_t stream)
{
    const float* x        = (const float*)d_in[0];
    const float* gumbel   = (const float*)d_in[1];
    const float* w0       = (const float*)d_in[2];
    const float* b0       = (const float*)d_in[3];
    const float* ln_g     = (const float*)d_in[4];
    const float* ln_b     = (const float*)d_in[5];
    const float* gate_w   = (const float*)d_in[6];
    const float* gate_b   = (const float*)d_in[7];
    const float* actor_w  = (const float*)d_in[8];
    const float* actor_b  = (const float*)d_in[9];
    const float* critic_w = (const float*)d_in[10];
    const float* critic_b = (const float*)d_in[11];
    const float* in_w[2]   = {(const float*)d_in[12], (const float*)d_in[22]};
    const float* in_b[2]   = {(const float*)d_in[13], (const float*)d_in[23]};
    const float* conv_w[2] = {(const float*)d_in[14], (const float*)d_in[24]};
    const float* conv_b[2] = {(const float*)d_in[15], (const float*)d_in[25]};
    const float* xp_w[2]   = {(const float*)d_in[16], (const float*)d_in[26]};
    const float* xp_b[2]   = {(const float*)d_in[17], (const float*)d_in[27]};
    const float* dt_w[2]   = {(const float*)d_in[18], (const float*)d_in[28]};
    const float* dt_b[2]   = {(const float*)d_in[19], (const float*)d_in[29]};
    const float* out_w[2]  = {(const float*)d_in[20], (const float*)d_in[30]};
    const float* out_b[2]  = {(const float*)d_in[21], (const float*)d_in[31]};

    // Per-row scratch: union(xb fp32 | xchi)(2048) + hhi/hlo(2048) + Abig hi(2048) = 6144 B
    int CB = 512;
    while (CB > 1 && (size_t)CB * LL * 6144 + (16u << 20) > ws_size) CB >>= 1;
    const int rows = CB * LL;
    const size_t CSZ = (size_t)rows * HD;        // elements per 512-wide buffer

    char* p = (char*)d_ws;
    float* xb = (float*)p;                       // union with xchi (phases don't overlap)
    unsigned short* xchi = (unsigned short*)p;   p += CSZ * 4;
    unsigned short* hhi = (unsigned short*)p;    p += CSZ * 2;
    unsigned short* hlo = (unsigned short*)p;    p += CSZ * 2;
    unsigned short* Abig_hi = (unsigned short*)p; p += CSZ * 2 * 2;  // rows x 1024 bf16
    unsigned short* wtb = (unsigned short*)p;  p += (size_t)8 * 524288 * 2;
    unsigned short* iwh[2] = {wtb,            wtb + 4*524288};
    unsigned short* iwl[2] = {wtb +   524288, wtb + 5*524288};
    unsigned short* owh[2] = {wtb + 2*524288, wtb + 6*524288};
    unsigned short* owl[2] = {wtb + 3*524288, wtb + 7*524288};
    unsigned short* Uhi[2] = {(unsigned short*)p, (unsigned short*)p + 262144}; p += 262144u * 2 * 2;
    unsigned short* Ulo[2] = {(unsigned short*)p, (unsigned short*)p + 262144}; p += 262144u * 2 * 2;
    float* biasU[2] = {(float*)p, (float*)p + 512};           p += 1024 * 4;
    // regp2: (rows/4) x 512 fp32 — OVERLAYS Abig_hi (dead after MODE1; k_ln writes it after
    // MODE1 reads Abig; m=1's write is the one k_head consumes; all kernels serial on stream).
    float* regp2 = (float*)Abig_hi;

    // weight transforms: 3 launches
    k_cvt2<<<4096, 256, 0, stream>>>(in_w[0], in_w[1], iwh[0], iwl[0], iwh[1], iwl[1], 1024, 9);
    k_cvt2<<<4096, 256, 0, stream>>>(out_w[0], out_w[1], owh[0], owl[0], owh[1], owl[1], 512, 10);
    k_mkU2<<<2052, 256, 0, stream>>>(xp_w[0], dt_w[0], xp_b[0], dt_b[0],
                                     xp_w[1], dt_w[1], xp_b[1], dt_b[1],
                                     Uhi[0], Ulo[0], Uhi[1], Ulo[1], biasU[0], biasU[1]);

    const int nchunk = BB / CB;
    for (int c = 0; c < nchunk; ++c) {
        const float* xin = x + (size_t)c * CB * LL * FD;
        k_embed<<<rows*HD/256, 256, 0, stream>>>(xin, w0, b0, hhi, hlo);
        for (int m = 0; m < 2; ++m) {
            // in_proj + fused conv: A=hhi; z->Abig[:,512:] (hi), conv(xi)->xc (hi)
            k_mgemm<512, 0><<<dim3(rows/128, 8), 512, 0, stream>>>(
                hhi, iwh[m], iwl[m], in_b[m], conv_w[m], conv_b[m],
                nullptr, nullptr,
                nullptr, Abig_hi, xchi);
            // dt GEMM: A=xc; out = xc * softplus(xc@U + biasU) -> Abig[:,0:512] (hi)
            k_mgemm<512, 2><<<dim3(rows/128, 4), 512, 0, stream>>>(
                xchi, Uhi[m], Ulo[m], biasU[m], nullptr, nullptr,
                nullptr, nullptr,
                nullptr, Abig_hi, nullptr);
            // out_proj: A=Abig; out = Abig@out_w + out_b + resid(hhi/hlo) -> xb fp32
            k_mgemm<1024, 1><<<dim3(rows/128, 4), 512, 0, stream>>>(
                Abig_hi, owh[m], owl[m], out_b[m], nullptr, nullptr,
                hhi, hlo,
                xb, nullptr, nullptr);
            // LN(xb) -> hhi/hlo + per-4-row channel partials
            k_ln<<<rows/4, 256, 0, stream>>>(xb, ln_g, ln_b, hhi, hlo, regp2);
        }
        k_head<<<CB, 512, 0, stream>>>(hhi, hlo, regp2, gumbel, gate_w, gate_b,
                                       actor_w, actor_b, critic_w, critic_b,
                                       (float*)d_out, c*CB);
    }
}

// Round 15
// 1145.721 us; speedup vs baseline: 1.2897x; 1.1811x over previous
//
#include <hip/hip_runtime.h>
#include <math.h>

#define BB 512
#define LL 128
#define FD 8
#define HD 512
#define EPSV 1e-5f

typedef __attribute__((ext_vector_type(8))) __bf16 bf16x8;
typedef __attribute__((ext_vector_type(4))) float floatx4;
typedef __attribute__((ext_vector_type(8))) unsigned short us8;

__device__ __forceinline__ float silu_f(float x){ return x / (1.0f + expf(-x)); }
__device__ __forceinline__ float softplus_f(float x){ return (x > 20.0f) ? x : log1pf(expf(x)); }

__device__ __forceinline__ unsigned short f2bf(float x){
    union { float f; unsigned u; } v; v.f = x;
    unsigned r = v.u + 0x7fffu + ((v.u >> 16) & 1u);   // RNE
    return (unsigned short)(r >> 16);
}
__device__ __forceinline__ float bf2f(unsigned short h){
    union { unsigned u; float f; } v; v.u = ((unsigned)h) << 16; return v.f;
}
__device__ __forceinline__ void split_bf(float x, unsigned short* hi, unsigned short* lo){
    unsigned short h = f2bf(x);
    *hi = h;
    *lo = f2bf(x - bf2f(h));
}

// ---------------- embed: h = x @ w0 + b0 -> hi/lo bf16 (residual stream KEEPS the split) ----------------
__global__ __launch_bounds__(256) void k_embed(const float* __restrict__ x,
    const float* __restrict__ w0, const float* __restrict__ b0,
    unsigned short* __restrict__ hhi, unsigned short* __restrict__ hlo)
{
    int idx = blockIdx.x*256 + threadIdx.x;      // over rows*HD
    int c = idx & (HD-1);
    int row = idx >> 9;
    const float* xr = x + (size_t)row*FD;
    float acc = b0[c];
    #pragma unroll
    for (int f=0; f<FD; ++f) acc = fmaf(xr[f], w0[f*HD + c], acc);
    unsigned short hi, lo; split_bf(acc, &hi, &lo);
    hhi[idx] = hi; hlo[idx] = lo;
}

// ---------------- weight transpose for BOTH layers: W[K][N] -> Wt[N][K] bf16 (hi only) ----------------
// Round-28: weight lo-halves DROPPED (declared precision gamble — see k_mgemm comment).
__global__ __launch_bounds__(256) void k_cvt2(const float* __restrict__ W0,
    const float* __restrict__ W1,
    unsigned short* __restrict__ Th0, unsigned short* __restrict__ Th1,
    int N, int kbits)
{
    int total = N << kbits;
    int idx = blockIdx.x*256 + threadIdx.x;
    const float* W = W0; unsigned short* Th = Th0;
    if (idx >= total) { idx -= total; W = W1; Th = Th1; }
    int K = 1 << kbits;
    int n = idx >> kbits, k = idx & (K-1);
    Th[idx] = f2bf(W[(size_t)k*N + n]);
}

// ---------------- U = xp_w @ dt_w (512x512, B-layout [n][c]) + biasU, both layers (hi only) ----------------
__global__ __launch_bounds__(256) void k_mkU2(
    const float* __restrict__ xw0, const float* __restrict__ dw0,
    const float* __restrict__ xpb0, const float* __restrict__ dtb0,
    const float* __restrict__ xw1, const float* __restrict__ dw1,
    const float* __restrict__ xpb1, const float* __restrict__ dtb1,
    unsigned short* __restrict__ Uhi0, unsigned short* __restrict__ Uhi1,
    float* __restrict__ bU0, float* __restrict__ bU1)
{
    int blk = blockIdx.x, tid = threadIdx.x;
    if (blk < 2048) {
        int layer = blk >> 10;
        const float* xw = layer ? xw1 : xw0;
        const float* dw = layer ? dw1 : dw0;
        unsigned short* Uh = layer ? Uhi1 : Uhi0;
        int idx = (blk & 1023)*256 + tid;        // n*512 + c, c fastest
        int n = idx >> 9, c = idx & 511;
        float acc = 0.0f;
        #pragma unroll
        for (int j = 0; j < 16; ++j) acc = fmaf(xw[c*16 + j], dw[j*512 + n], acc);
        Uh[idx] = f2bf(acc);
    } else {
        int q = blk - 2048;                      // 0..3
        int layer = q >> 1;
        const float* xpb = layer ? xpb1 : xpb0;
        const float* dw  = layer ? dw1  : dw0;
        const float* dtb = layer ? dtb1 : dtb0;
        float* bU = layer ? bU1 : bU0;
        int n = (q & 1)*256 + tid;
        float acc = dtb[n];
        #pragma unroll
        for (int j = 0; j < 16; ++j) acc = fmaf(xpb[j], dw[j*512 + n], acc);
        bU[n] = acc;
    }
}

// ---------------- bf16 x bf16 MFMA GEMM, 128x128 tile, 8 waves, 16x16x32, BK=64 ----------------
// Round-28 (declared precision gamble, same class as the round-8 win): drop the WEIGHT lo-halves.
// GEMMs are now single-bf16 x single-bf16: 1 MFMA per fragment pair (was 2 — GEMM matrix work
// -50%), staging 6 -> 4 global_load_lds/K-step, LDS 48KB -> 32.5KB. Residual stream (h) keeps
// the hi/lo split everywhere it is accumulated (k_embed, MODE1 resid add, k_ln) — error model:
// weights gain ~0.4% rel err, comparable to the already-accepted bf16-A rounding; absmax
// predicted 0.02-0.05 (was 0.0156). Falsification gate: absmax fail -> revert to round-27
// anchor (1353us) and declare the structural plateau.
// Everything else identical to the anchor: M-fast grid (A-tile reuse pinned to one XCD's L2 —
// round-13's swap falsified the alternative), XOR chunk swizzle, fused epilogues.
// MODE 0 (in_proj, K=512, N=1024): A=hhi.
//    nBase<512  (z):  silu -> Abig[row][512+col] bf16 (hi only)
//    nBase>=512 (xi): fused conv3+silu -> xc[row][col-512] bf16 (hi only)
// MODE 1 (out_proj, K=1024, N=512): A=Abig; outF = v + bias + resid(hi/lo) fp32
// MODE 2 (dt, K=512, N=512): A=xc; out = xc * softplus(v + biasU) -> Abig[row][col] (hi only)
template<int KDIM, int MODE>
__global__ __launch_bounds__(512, 4) void k_mgemm(
    const unsigned short* __restrict__ Ahi,
    const unsigned short* __restrict__ Bhi,
    const float* __restrict__ bias,
    const float* __restrict__ cw, const float* __restrict__ cb,
    const unsigned short* __restrict__ rhi, const unsigned short* __restrict__ rlo,
    float* __restrict__ outF,
    unsigned short* __restrict__ oAhi,
    unsigned short* __restrict__ xchi)
{
    // LDS (ushort elems): A [0,8192) | Bhi [8192,16384) = 32768 B staging.
    // Epilogue reuses the buffer as sc[128][65] fp32 = 33280 B -> smem = 33280.
    __shared__ __align__(16) char smem[33280];
    unsigned short* lds = (unsigned short*)smem;
    const int tid  = threadIdx.x;
    const int wv   = tid >> 6, lane = tid & 63;
    const int quad = lane >> 4, l16 = lane & 15;
    const size_t mBase = (size_t)blockIdx.x * 128;   // M fast — M-tile m pins to XCD m%8; A reuse on-XCD
    const int nBase = blockIdx.y * 128;
    const int wm = (wv & 3) * 32, wn = (wv >> 2) * 64;

    floatx4 acc[2][4] = {};

    const int rowIn = lane >> 2;                 // 0..15
    const int kofs  = ((lane & 3) ^ ((lane >> 3) & 3)) * 8;  // swizzled source k-chunk
    const int qx    = (quad ^ ((l16 >> 1) & 3)) * 8;         // swizzled read k-chunk
    const unsigned short* gsrc[2];
    gsrc[0] = Ahi + mBase * KDIM;
    gsrc[1] = Bhi + (size_t)nBase * KDIM;

    for (int k0 = 0; k0 < KDIM; k0 += 64) {
        // stage 2 operand tiles x 2 k-sub-tiles; 4 global_load_lds per thread
        #pragma unroll
        for (int b = 0; b < 2; ++b) {
            #pragma unroll
            for (int s = 0; s < 2; ++s) {
                int row = wv * 16 + rowIn;
                const unsigned short* g = gsrc[b] + (size_t)row * KDIM + k0 + s*32 + kofs;
                unsigned short* l = &lds[b * 8192 + s * 4096 + wv * 512]; // +lane*16B implicit
                __builtin_amdgcn_global_load_lds(
                    (const __attribute__((address_space(1))) void*)g,
                    (__attribute__((address_space(3))) void*)l, 16, 0, 0);
            }
        }
        __syncthreads();
        #pragma unroll
        for (int s = 0; s < 2; ++s) {
            const int kb = s * 4096;
            bf16x8 ah[2];
            #pragma unroll
            for (int i = 0; i < 2; ++i) {
                int am = wm + 16*i + l16;
                ah[i] = *(const bf16x8*)&lds[kb + am*32 + qx];
            }
            #pragma unroll
            for (int j = 0; j < 4; ++j) {
                int bn = wn + 16*j + l16;
                bf16x8 bh = *(const bf16x8*)&lds[8192 + kb + bn*32 + qx];
                #pragma unroll
                for (int i = 0; i < 2; ++i)
                    acc[i][j] = __builtin_amdgcn_mfma_f32_16x16x32_bf16(ah[i], bh, acc[i][j], 0, 0, 0);
            }
        }
        __syncthreads();
    }

    // ---- unified coalesced epilogue: two 64-col halves through LDS (stride 65) ----
    float* sc = (float*)smem;
    const int q8 = (tid & 7) * 8;                // col chunk within half
    const int rg = tid >> 3;                     // 0..63 row group
    #pragma unroll
    for (int half = 0; half < 2; ++half) {
        __syncthreads();
        if ((wv >> 2) == half) {                 // 4 waves owning this half stage v+bias
            #pragma unroll
            for (int i = 0; i < 2; ++i)
                #pragma unroll
                for (int r = 0; r < 4; ++r) {
                    int rl = wm + 16*i + quad*4 + r;
                    #pragma unroll
                    for (int j = 0; j < 4; ++j) {
                        int cl = 16*j + l16;
                        sc[rl*65 + cl] = acc[i][j][r] + bias[nBase + half*64 + cl];
                    }
                }
        }
        __syncthreads();
        #pragma unroll
        for (int pss = 0; pss < 2; ++pss) {
            int l = pss*64 + rg;                 // row within 128-row tile
            size_t grow = mBase + l;
            if (MODE == 0) {
                if (nBase < 512) {               // z half: silu -> Abig[:,512+col] (hi only)
                    int gcol = nBase + half*64 + q8;
                    us8 hh;
                    #pragma unroll
                    for (int k = 0; k < 8; ++k)
                        hh[k] = f2bf(silu_f(sc[l*65 + q8 + k]));
                    *(us8*)(oAhi + grow*1024 + 512 + gcol) = hh;
                } else {                         // xi half: conv3+silu -> xc (hi only)
                    int gcol = (nBase - 512) + half*64 + q8;
                    us8 hh;
                    #pragma unroll
                    for (int k = 0; k < 8; ++k) {
                        int cc = q8 + k;
                        float xm = (l > 0)   ? sc[(l-1)*65 + cc] : 0.0f;
                        float x0 = sc[l*65 + cc];
                        float xp = (l < 127) ? sc[(l+1)*65 + cc] : 0.0f;
                        int gc = gcol + k;
                        float v = cb[gc];
                        v = fmaf(xm, cw[gc*3+0], v);
                        v = fmaf(x0, cw[gc*3+1], v);
                        v = fmaf(xp, cw[gc*3+2], v);
                        hh[k] = f2bf(silu_f(v));
                    }
                    *(us8*)(xchi + grow*512 + gcol) = hh;
                }
            } else if (MODE == 1) {              // fp32 out = (v+bias) + resid(hi/lo), float4 x2
                int gcol = nBase + half*64 + q8;
                us8 rh = *(const us8*)(rhi + grow*512 + gcol);
                us8 rl = *(const us8*)(rlo + grow*512 + gcol);
                float o[8];
                #pragma unroll
                for (int k = 0; k < 8; ++k)
                    o[k] = sc[l*65 + q8 + k] + (bf2f(rh[k]) + bf2f(rl[k]));
                float4 o0, o1;
                o0.x=o[0]; o0.y=o[1]; o0.z=o[2]; o0.w=o[3];
                o1.x=o[4]; o1.y=o[5]; o1.z=o[6]; o1.w=o[7];
                *(float4*)(outF + grow*512 + gcol)     = o0;
                *(float4*)(outF + grow*512 + gcol + 4) = o1;
            } else {                             // MODE 2: xid = xc*softplus(v) (hi only out)
                int gcol = nBase + half*64 + q8;
                us8 xh = *(const us8*)(Ahi + grow*512 + gcol);
                us8 hh;
                #pragma unroll
                for (int k = 0; k < 8; ++k) {
                    float o = bf2f(xh[k]) * softplus_f(sc[l*65 + q8 + k]);
                    hh[k] = f2bf(o);
                }
                *(us8*)(oAhi + grow*1024 + gcol) = hh;
            }
        }
    }
}

// ---------------- layernorm of pre-summed row (resid already added in MODE1 epilogue) ----------------
// Emits hi/lo bf16 + per-block (4-row) channel partials -> regp2; k_head sums 32 partials/batch.
__global__ __launch_bounds__(256) void k_ln(const float* __restrict__ in,
    const float* __restrict__ g, const float* __restrict__ b,
    unsigned short* ohi, unsigned short* olo, float* __restrict__ regp2)
{
    __shared__ float sacc[4][512];
    int wv = threadIdx.x >> 6, lane = threadIdx.x & 63;
    size_t row = (size_t)blockIdx.x * 4 + wv;
    size_t base = row*512 + lane*8;
    float4 v0 = *(const float4*)(in + base);
    float4 v1 = *(const float4*)(in + base + 4);
    float vals[8] = {v0.x,v0.y,v0.z,v0.w,v1.x,v1.y,v1.z,v1.w};
    float s = 0.f, q = 0.f;
    #pragma unroll
    for (int k = 0; k < 8; ++k) { s += vals[k]; q += vals[k]*vals[k]; }
    #pragma unroll
    for (int off = 32; off; off >>= 1) { s += __shfl_xor(s, off); q += __shfl_xor(q, off); }
    float mu = s * (1.0f/512.0f);
    float rs = rsqrtf(q*(1.0f/512.0f) - mu*mu + EPSV);
    const float* gp = g + lane*8;
    const float* bp = b + lane*8;
    float4 g0 = *(const float4*)gp, g1 = *(const float4*)(gp+4);
    float4 b0 = *(const float4*)bp, b1 = *(const float4*)(bp+4);
    float gs[8] = {g0.x,g0.y,g0.z,g0.w,g1.x,g1.y,g1.z,g1.w};
    float bs[8] = {b0.x,b0.y,b0.z,b0.w,b1.x,b1.y,b1.z,b1.w};
    us8 hh, ll;
    #pragma unroll
    for (int k = 0; k < 8; ++k) {
        float o = (vals[k] - mu) * rs * gs[k] + bs[k];
        sacc[wv][lane*8 + k] = o;
        unsigned short hi, lo; split_bf(o, &hi, &lo);
        hh[k] = hi; ll[k] = lo;
    }
    *(us8*)(ohi + base) = hh;
    *(us8*)(olo + base) = ll;
    __syncthreads();
    int ch = threadIdx.x * 2;
    float s0 = (sacc[0][ch]   + sacc[1][ch])   + (sacc[2][ch]   + sacc[3][ch]);
    float s1 = (sacc[0][ch+1] + sacc[1][ch+1]) + (sacc[2][ch+1] + sacc[3][ch+1]);
    float2 o2; o2.x = s0; o2.y = s1;
    *(float2*)(regp2 + (size_t)blockIdx.x*512 + ch) = o2;
}

// ---------------- head: reg from k_ln partials; gate softmax+argmax; expert select ----------------
__global__ __launch_bounds__(512) void k_head(
    const unsigned short* __restrict__ hhi, const unsigned short* __restrict__ hlo,
    const float* __restrict__ regp2,
    const float* __restrict__ gumbel, const float* __restrict__ gate_w,
    const float* __restrict__ gate_b, const float* __restrict__ actor_w,
    const float* __restrict__ actor_b, const float* __restrict__ critic_w,
    const float* __restrict__ critic_b, float* __restrict__ out, int bofs)
{
    __shared__ float sred[8][4];
    __shared__ float sg;
    __shared__ int sestar;
    int bl = blockIdx.x, tid = threadIdx.x;      // tid = channel
    int b = bofs + bl;
    size_t base = (size_t)bl * LL * HD;
    const float* rp = regp2 + (size_t)bl*32*512; // 32 partial blocks per batch (128 rows / 4)
    float r0 = 0.0f;
    #pragma unroll
    for (int p = 0; p < 32; ++p) r0 += rp[p*512 + tid];
    r0 *= (1.0f/LL);
    size_t od = base + (LL-1)*HD + tid;
    float dec0 = bf2f(hhi[od]) + bf2f(hlo[od]);

    int lane = tid & 63, wid = tid >> 6;
    float p[4];
    #pragma unroll
    for (int e = 0; e < 4; ++e) p[e] = r0 * gate_w[tid*4 + e];
    #pragma unroll
    for (int e = 0; e < 4; ++e) {
        float v = p[e];
        for (int off = 32; off; off >>= 1) v += __shfl_down(v, off);
        p[e] = v;
    }
    if (!lane) { for (int e = 0; e < 4; ++e) sred[wid][e] = p[e]; }
    __syncthreads();
    if (!tid) {
        float ge[4]; float mx = -1e30f;
        for (int e = 0; e < 4; ++e) {
            float acc = gate_b[e] + gumbel[b*4 + e];
            for (int w = 0; w < 8; ++w) acc += sred[w][e];
            ge[e] = acc;
            if (acc > mx) mx = acc;
        }
        float ys[4], den = 0.f;
        for (int e = 0; e < 4; ++e) { ys[e] = expf(ge[e] - mx); den += ys[e]; }
        int estar = 0; float best = ge[0];
        for (int e = 1; e < 4; ++e) if (ge[e] > best) { best = ge[e]; estar = e; }
        float ye = ys[estar] / den;
        float gv = (1.0f + ye) - ye;             // exactly as reference
        for (int e = 0; e < 4; ++e) out[2048 + b*4 + e] = (e == estar) ? gv : 0.0f;
        sg = gv; sestar = estar;
    }
    __syncthreads();
    float gv = sg; int estar = sestar;
    const float* aw  = actor_w  + (size_t)estar * HD * 3;
    const float* cwp = critic_w + (size_t)estar * HD;
    float q[4];
    #pragma unroll
    for (int a = 0; a < 3; ++a) q[a] = dec0 * aw[tid*3 + a];
    q[3] = dec0 * cwp[tid];
    #pragma unroll
    for (int e = 0; e < 4; ++e) {
        float v = q[e];
        for (int off = 32; off; off >>= 1) v += __shfl_down(v, off);
        q[e] = v;
    }
    __syncthreads();
    if (!lane) { for (int e = 0; e < 4; ++e) sred[wid][e] = q[e]; }
    __syncthreads();
    if (!tid) {
        for (int a = 0; a < 3; ++a) {
            float acc = actor_b[estar*3 + a];
            for (int w = 0; w < 8; ++w) acc += sred[w][a];
            out[b*3 + a] = gv * acc;
        }
        float acc = critic_b[estar];
        for (int w = 0; w < 8; ++w) acc += sred[w][3];
        out[1536 + b] = gv * acc;
    }
}

extern "C" void kernel_launch(void* const* d_in, const int* in_sizes, int n_in,
                              void* d_out, int out_size, void* d_ws, size_t ws_size,
                              hipStream_t stream)
{
    const float* x        = (const float*)d_in[0];
    const float* gumbel   = (const float*)d_in[1];
    const float* w0       = (const float*)d_in[2];
    const float* b0       = (const float*)d_in[3];
    const float* ln_g     = (const float*)d_in[4];
    const float* ln_b     = (const float*)d_in[5];
    const float* gate_w   = (const float*)d_in[6];
    const float* gate_b   = (const float*)d_in[7];
    const float* actor_w  = (const float*)d_in[8];
    const float* actor_b  = (const float*)d_in[9];
    const float* critic_w = (const float*)d_in[10];
    const float* critic_b = (const float*)d_in[11];
    const float* in_w[2]   = {(const float*)d_in[12], (const float*)d_in[22]};
    const float* in_b[2]   = {(const float*)d_in[13], (const float*)d_in[23]};
    const float* conv_w[2] = {(const float*)d_in[14], (const float*)d_in[24]};
    const float* conv_b[2] = {(const float*)d_in[15], (const float*)d_in[25]};
    const float* xp_w[2]   = {(const float*)d_in[16], (const float*)d_in[26]};
    const float* xp_b[2]   = {(const float*)d_in[17], (const float*)d_in[27]};
    const float* dt_w[2]   = {(const float*)d_in[18], (const float*)d_in[28]};
    const float* dt_b[2]   = {(const float*)d_in[19], (const float*)d_in[29]};
    const float* out_w[2]  = {(const float*)d_in[20], (const float*)d_in[30]};
    const float* out_b[2]  = {(const float*)d_in[21], (const float*)d_in[31]};

    // Per-row scratch: union(xb fp32 | xchi)(2048) + hhi/hlo(2048) + Abig hi(2048) = 6144 B
    int CB = 512;
    while (CB > 1 && (size_t)CB * LL * 6144 + (16u << 20) > ws_size) CB >>= 1;
    const int rows = CB * LL;
    const size_t CSZ = (size_t)rows * HD;        // elements per 512-wide buffer

    char* p = (char*)d_ws;
    float* xb = (float*)p;                       // union with xchi (phases don't overlap)
    unsigned short* xchi = (unsigned short*)p;   p += CSZ * 4;
    unsigned short* hhi = (unsigned short*)p;    p += CSZ * 2;
    unsigned short* hlo = (unsigned short*)p;    p += CSZ * 2;
    unsigned short* Abig_hi = (unsigned short*)p; p += CSZ * 2 * 2;  // rows x 1024 bf16
    unsigned short* wtb = (unsigned short*)p;  p += (size_t)4 * 524288 * 2;  // hi-only weights
    unsigned short* iwh[2] = {wtb,            wtb + 2*524288};
    unsigned short* owh[2] = {wtb +  524288,  wtb + 3*524288};
    unsigned short* Uhi[2] = {(unsigned short*)p, (unsigned short*)p + 262144}; p += 262144u * 2 * 2;
    float* biasU[2] = {(float*)p, (float*)p + 512};           p += 1024 * 4;
    // regp2: (rows/4) x 512 fp32 — OVERLAYS Abig_hi (dead after MODE1; k_ln writes it after
    // MODE1 reads Abig; m=1's write is the one k_head consumes; all kernels serial on stream).
    float* regp2 = (float*)Abig_hi;

    // weight transforms: 3 launches (hi-only outputs)
    k_cvt2<<<4096, 256, 0, stream>>>(in_w[0], in_w[1], iwh[0], iwh[1], 1024, 9);
    k_cvt2<<<4096, 256, 0, stream>>>(out_w[0], out_w[1], owh[0], owh[1], 512, 10);
    k_mkU2<<<2052, 256, 0, stream>>>(xp_w[0], dt_w[0], xp_b[0], dt_b[0],
                                     xp_w[1], dt_w[1], xp_b[1], dt_b[1],
                                     Uhi[0], Uhi[1], biasU[0], biasU[1]);

    const int nchunk = BB / CB;
    for (int c = 0; c < nchunk; ++c) {
        const float* xin = x + (size_t)c * CB * LL * FD;
        k_embed<<<rows*HD/256, 256, 0, stream>>>(xin, w0, b0, hhi, hlo);
        for (int m = 0; m < 2; ++m) {
            // in_proj + fused conv: A=hhi; z->Abig[:,512:] (hi), conv(xi)->xc (hi)
            k_mgemm<512, 0><<<dim3(rows/128, 8), 512, 0, stream>>>(
                hhi, iwh[m], in_b[m], conv_w[m], conv_b[m],
                nullptr, nullptr,
                nullptr, Abig_hi, xchi);
            // dt GEMM: A=xc; out = xc * softplus(xc@U + biasU) -> Abig[:,0:512] (hi)
            k_mgemm<512, 2><<<dim3(rows/128, 4), 512, 0, stream>>>(
                xchi, Uhi[m], biasU[m], nullptr, nullptr,
                nullptr, nullptr,
                nullptr, Abig_hi, nullptr);
            // out_proj: A=Abig; out = Abig@out_w + out_b + resid(hhi/hlo) -> xb fp32
            k_mgemm<1024, 1><<<dim3(rows/128, 4), 512, 0, stream>>>(
                Abig_hi, owh[m], out_b[m], nullptr, nullptr,
                hhi, hlo,
                xb, nullptr, nullptr);
            // LN(xb) -> hhi/hlo + per-4-row channel partials
            k_ln<<<rows/4, 256, 0, stream>>>(xb, ln_g, ln_b, hhi, hlo, regp2);
        }
        k_head<<<CB, 512, 0, stream>>>(hhi, hlo, regp2, gumbel, gate_w, gate_b,
                                       actor_w, actor_b, critic_w, critic_b,
                                       (float*)d_out, c*CB);
    }
}

// Round 16
// 1070.930 us; speedup vs baseline: 1.3798x; 1.0698x over previous
//
#include <hip/hip_runtime.h>
#include <math.h>

#define BB 512
#define LL 128
#define FD 8
#define HD 512
#define EPSV 1e-5f

typedef __attribute__((ext_vector_type(8))) __bf16 bf16x8;
typedef __attribute__((ext_vector_type(4))) float floatx4;
typedef __attribute__((ext_vector_type(8))) unsigned short us8;

__device__ __forceinline__ float silu_f(float x){ return x / (1.0f + expf(-x)); }
__device__ __forceinline__ float softplus_f(float x){ return (x > 20.0f) ? x : log1pf(expf(x)); }

__device__ __forceinline__ unsigned short f2bf(float x){
    union { float f; unsigned u; } v; v.f = x;
    unsigned r = v.u + 0x7fffu + ((v.u >> 16) & 1u);   // RNE
    return (unsigned short)(r >> 16);
}
__device__ __forceinline__ float bf2f(unsigned short h){
    union { unsigned u; float f; } v; v.u = ((unsigned)h) << 16; return v.f;
}

// ---------------- embed: h = x @ w0 + b0 -> bf16 (hi only; round-29 drops the lo residual) ----------------
__global__ __launch_bounds__(256) void k_embed(const float* __restrict__ x,
    const float* __restrict__ w0, const float* __restrict__ b0,
    unsigned short* __restrict__ hhi)
{
    int idx = blockIdx.x*256 + threadIdx.x;      // over rows*HD
    int c = idx & (HD-1);
    int row = idx >> 9;
    const float* xr = x + (size_t)row*FD;
    float acc = b0[c];
    #pragma unroll
    for (int f=0; f<FD; ++f) acc = fmaf(xr[f], w0[f*HD + c], acc);
    hhi[idx] = f2bf(acc);
}

// ---------------- weight transpose for BOTH layers: W[K][N] -> Wt[N][K] bf16 (hi only) ----------------
__global__ __launch_bounds__(256) void k_cvt2(const float* __restrict__ W0,
    const float* __restrict__ W1,
    unsigned short* __restrict__ Th0, unsigned short* __restrict__ Th1,
    int N, int kbits)
{
    int total = N << kbits;
    int idx = blockIdx.x*256 + threadIdx.x;
    const float* W = W0; unsigned short* Th = Th0;
    if (idx >= total) { idx -= total; W = W1; Th = Th1; }
    int K = 1 << kbits;
    int n = idx >> kbits, k = idx & (K-1);
    Th[idx] = f2bf(W[(size_t)k*N + n]);
}

// ---------------- U = xp_w @ dt_w (512x512, B-layout [n][c]) + biasU, both layers (hi only) ----------------
__global__ __launch_bounds__(256) void k_mkU2(
    const float* __restrict__ xw0, const float* __restrict__ dw0,
    const float* __restrict__ xpb0, const float* __restrict__ dtb0,
    const float* __restrict__ xw1, const float* __restrict__ dw1,
    const float* __restrict__ xpb1, const float* __restrict__ dtb1,
    unsigned short* __restrict__ Uhi0, unsigned short* __restrict__ Uhi1,
    float* __restrict__ bU0, float* __restrict__ bU1)
{
    int blk = blockIdx.x, tid = threadIdx.x;
    if (blk < 2048) {
        int layer = blk >> 10;
        const float* xw = layer ? xw1 : xw0;
        const float* dw = layer ? dw1 : dw0;
        unsigned short* Uh = layer ? Uhi1 : Uhi0;
        int idx = (blk & 1023)*256 + tid;        // n*512 + c, c fastest
        int n = idx >> 9, c = idx & 511;
        float acc = 0.0f;
        #pragma unroll
        for (int j = 0; j < 16; ++j) acc = fmaf(xw[c*16 + j], dw[j*512 + n], acc);
        Uh[idx] = f2bf(acc);
    } else {
        int q = blk - 2048;                      // 0..3
        int layer = q >> 1;
        const float* xpb = layer ? xpb1 : xpb0;
        const float* dw  = layer ? dw1  : dw0;
        const float* dtb = layer ? dtb1 : dtb0;
        float* bU = layer ? bU1 : bU0;
        int n = (q & 1)*256 + tid;
        float acc = dtb[n];
        #pragma unroll
        for (int j = 0; j < 16; ++j) acc = fmaf(xpb[j], dw[j*512 + n], acc);
        bU[n] = acc;
    }
}

// ---------------- bf16 x bf16 MFMA GEMM, 128x128 tile, 8 waves, 16x16x32, BK=64 ----------------
// Round-29 (residual-format change, one lever): drop the LO half of the residual stream.
// Evidence: absmax stayed EXACTLY 0.015625 through both prior precision cuts — error is
// quantization-dominated in the output path, not GEMM-precision-dominated. The output path is
// now IMPROVED (k_ln emits fp32 decf for the decision row; k_head uses it instead of hi+lo),
// and hlo's only remaining role — the inter-layer residual carry — tolerates bf16 (0.2% rel,
// washes into accepted GEMM rounding). Saves ~170MB/run (k_embed/k_ln writes, MODE1 reads).
// Falsification gate: absmax fail -> revert to round-15 source (1146us) and declare plateau.
// K-loop/grid/swizzle identical to round-15 (M-fast: A-tile reuse pinned to one XCD's L2).
// MODE 0 (in_proj, K=512, N=1024): A=hhi.
//    nBase<512  (z):  silu -> Abig[row][512+col] bf16
//    nBase>=512 (xi): fused conv3+silu -> xc[row][col-512] bf16
// MODE 1 (out_proj, K=1024, N=512): A=Abig; outF = v + bias + resid(bf16 hi) fp32
// MODE 2 (dt, K=512, N=512): A=xc; out = xc * softplus(v + biasU) -> Abig[row][col]
template<int KDIM, int MODE>
__global__ __launch_bounds__(512, 4) void k_mgemm(
    const unsigned short* __restrict__ Ahi,
    const unsigned short* __restrict__ Bhi,
    const float* __restrict__ bias,
    const float* __restrict__ cw, const float* __restrict__ cb,
    const unsigned short* __restrict__ rhi,
    float* __restrict__ outF,
    unsigned short* __restrict__ oAhi,
    unsigned short* __restrict__ xchi)
{
    // LDS (ushort elems): A [0,8192) | Bhi [8192,16384) = 32768 B staging.
    // Epilogue reuses the buffer as sc[128][65] fp32 = 33280 B -> smem = 33280.
    __shared__ __align__(16) char smem[33280];
    unsigned short* lds = (unsigned short*)smem;
    const int tid  = threadIdx.x;
    const int wv   = tid >> 6, lane = tid & 63;
    const int quad = lane >> 4, l16 = lane & 15;
    const size_t mBase = (size_t)blockIdx.x * 128;   // M fast — M-tile m pins to XCD m%8
    const int nBase = blockIdx.y * 128;
    const int wm = (wv & 3) * 32, wn = (wv >> 2) * 64;

    floatx4 acc[2][4] = {};

    const int rowIn = lane >> 2;                 // 0..15
    const int kofs  = ((lane & 3) ^ ((lane >> 3) & 3)) * 8;  // swizzled source k-chunk
    const int qx    = (quad ^ ((l16 >> 1) & 3)) * 8;         // swizzled read k-chunk
    const unsigned short* gsrc[2];
    gsrc[0] = Ahi + mBase * KDIM;
    gsrc[1] = Bhi + (size_t)nBase * KDIM;

    for (int k0 = 0; k0 < KDIM; k0 += 64) {
        // stage 2 operand tiles x 2 k-sub-tiles; 4 global_load_lds per thread
        #pragma unroll
        for (int b = 0; b < 2; ++b) {
            #pragma unroll
            for (int s = 0; s < 2; ++s) {
                int row = wv * 16 + rowIn;
                const unsigned short* g = gsrc[b] + (size_t)row * KDIM + k0 + s*32 + kofs;
                unsigned short* l = &lds[b * 8192 + s * 4096 + wv * 512]; // +lane*16B implicit
                __builtin_amdgcn_global_load_lds(
                    (const __attribute__((address_space(1))) void*)g,
                    (__attribute__((address_space(3))) void*)l, 16, 0, 0);
            }
        }
        __syncthreads();
        #pragma unroll
        for (int s = 0; s < 2; ++s) {
            const int kb = s * 4096;
            bf16x8 ah[2];
            #pragma unroll
            for (int i = 0; i < 2; ++i) {
                int am = wm + 16*i + l16;
                ah[i] = *(const bf16x8*)&lds[kb + am*32 + qx];
            }
            #pragma unroll
            for (int j = 0; j < 4; ++j) {
                int bn = wn + 16*j + l16;
                bf16x8 bh = *(const bf16x8*)&lds[8192 + kb + bn*32 + qx];
                #pragma unroll
                for (int i = 0; i < 2; ++i)
                    acc[i][j] = __builtin_amdgcn_mfma_f32_16x16x32_bf16(ah[i], bh, acc[i][j], 0, 0, 0);
            }
        }
        __syncthreads();
    }

    // ---- unified coalesced epilogue: two 64-col halves through LDS (stride 65) ----
    float* sc = (float*)smem;
    const int q8 = (tid & 7) * 8;                // col chunk within half
    const int rg = tid >> 3;                     // 0..63 row group
    #pragma unroll
    for (int half = 0; half < 2; ++half) {
        __syncthreads();
        if ((wv >> 2) == half) {                 // 4 waves owning this half stage v+bias
            #pragma unroll
            for (int i = 0; i < 2; ++i)
                #pragma unroll
                for (int r = 0; r < 4; ++r) {
                    int rl = wm + 16*i + quad*4 + r;
                    #pragma unroll
                    for (int j = 0; j < 4; ++j) {
                        int cl = 16*j + l16;
                        sc[rl*65 + cl] = acc[i][j][r] + bias[nBase + half*64 + cl];
                    }
                }
        }
        __syncthreads();
        #pragma unroll
        for (int pss = 0; pss < 2; ++pss) {
            int l = pss*64 + rg;                 // row within 128-row tile
            size_t grow = mBase + l;
            if (MODE == 0) {
                if (nBase < 512) {               // z half: silu -> Abig[:,512+col]
                    int gcol = nBase + half*64 + q8;
                    us8 hh;
                    #pragma unroll
                    for (int k = 0; k < 8; ++k)
                        hh[k] = f2bf(silu_f(sc[l*65 + q8 + k]));
                    *(us8*)(oAhi + grow*1024 + 512 + gcol) = hh;
                } else {                         // xi half: conv3+silu -> xc
                    int gcol = (nBase - 512) + half*64 + q8;
                    us8 hh;
                    #pragma unroll
                    for (int k = 0; k < 8; ++k) {
                        int cc = q8 + k;
                        float xm = (l > 0)   ? sc[(l-1)*65 + cc] : 0.0f;
                        float x0 = sc[l*65 + cc];
                        float xp = (l < 127) ? sc[(l+1)*65 + cc] : 0.0f;
                        int gc = gcol + k;
                        float v = cb[gc];
                        v = fmaf(xm, cw[gc*3+0], v);
                        v = fmaf(x0, cw[gc*3+1], v);
                        v = fmaf(xp, cw[gc*3+2], v);
                        hh[k] = f2bf(silu_f(v));
                    }
                    *(us8*)(xchi + grow*512 + gcol) = hh;
                }
            } else if (MODE == 1) {              // fp32 out = (v+bias) + resid(bf16), float4 x2
                int gcol = nBase + half*64 + q8;
                us8 rh = *(const us8*)(rhi + grow*512 + gcol);
                float o[8];
                #pragma unroll
                for (int k = 0; k < 8; ++k)
                    o[k] = sc[l*65 + q8 + k] + bf2f(rh[k]);
                float4 o0, o1;
                o0.x=o[0]; o0.y=o[1]; o0.z=o[2]; o0.w=o[3];
                o1.x=o[4]; o1.y=o[5]; o1.z=o[6]; o1.w=o[7];
                *(float4*)(outF + grow*512 + gcol)     = o0;
                *(float4*)(outF + grow*512 + gcol + 4) = o1;
            } else {                             // MODE 2: xid = xc*softplus(v)
                int gcol = nBase + half*64 + q8;
                us8 xh = *(const us8*)(Ahi + grow*512 + gcol);
                us8 hh;
                #pragma unroll
                for (int k = 0; k < 8; ++k) {
                    float o = bf2f(xh[k]) * softplus_f(sc[l*65 + q8 + k]);
                    hh[k] = f2bf(o);
                }
                *(us8*)(oAhi + grow*1024 + gcol) = hh;
            }
        }
    }
}

// ---------------- layernorm of pre-summed row; emit bf16 (hi) + partials + fp32 decision row ----
// Block = 4 consecutive rows of ONE batch. Emits per-4-row channel partials -> regp2 (k_head
// sums 32/batch) and, for the LAST row of each 128-row batch, the exact fp32 LN output -> decf
// (k_head's dec0 — now MORE precise than the old hi+lo reconstruction).
__global__ __launch_bounds__(256) void k_ln(const float* __restrict__ in,
    const float* __restrict__ g, const float* __restrict__ b,
    unsigned short* ohi, float* __restrict__ regp2, float* __restrict__ decf)
{
    __shared__ float sacc[4][512];
    int wv = threadIdx.x >> 6, lane = threadIdx.x & 63;
    size_t row = (size_t)blockIdx.x * 4 + wv;
    size_t base = row*512 + lane*8;
    float4 v0 = *(const float4*)(in + base);
    float4 v1 = *(const float4*)(in + base + 4);
    float vals[8] = {v0.x,v0.y,v0.z,v0.w,v1.x,v1.y,v1.z,v1.w};
    float s = 0.f, q = 0.f;
    #pragma unroll
    for (int k = 0; k < 8; ++k) { s += vals[k]; q += vals[k]*vals[k]; }
    #pragma unroll
    for (int off = 32; off; off >>= 1) { s += __shfl_xor(s, off); q += __shfl_xor(q, off); }
    float mu = s * (1.0f/512.0f);
    float rs = rsqrtf(q*(1.0f/512.0f) - mu*mu + EPSV);
    const float* gp = g + lane*8;
    const float* bp = b + lane*8;
    float4 g0 = *(const float4*)gp, g1 = *(const float4*)(gp+4);
    float4 b0 = *(const float4*)bp, b1 = *(const float4*)(bp+4);
    float gs[8] = {g0.x,g0.y,g0.z,g0.w,g1.x,g1.y,g1.z,g1.w};
    float bs[8] = {b0.x,b0.y,b0.z,b0.w,b1.x,b1.y,b1.z,b1.w};
    us8 hh;
    float ov[8];
    #pragma unroll
    for (int k = 0; k < 8; ++k) {
        float o = (vals[k] - mu) * rs * gs[k] + bs[k];
        ov[k] = o;
        sacc[wv][lane*8 + k] = o;
        hh[k] = f2bf(o);
    }
    *(us8*)(ohi + base) = hh;
    if (wv == 3 && (blockIdx.x & 31) == 31) {    // last row of this 128-row batch: fp32 decision row
        size_t batch = row >> 7;
        float4 d0, d1;
        d0.x=ov[0]; d0.y=ov[1]; d0.z=ov[2]; d0.w=ov[3];
        d1.x=ov[4]; d1.y=ov[5]; d1.z=ov[6]; d1.w=ov[7];
        *(float4*)(decf + batch*512 + lane*8)     = d0;
        *(float4*)(decf + batch*512 + lane*8 + 4) = d1;
    }
    __syncthreads();
    int ch = threadIdx.x * 2;
    float s0 = (sacc[0][ch]   + sacc[1][ch])   + (sacc[2][ch]   + sacc[3][ch]);
    float s1 = (sacc[0][ch+1] + sacc[1][ch+1]) + (sacc[2][ch+1] + sacc[3][ch+1]);
    float2 o2; o2.x = s0; o2.y = s1;
    *(float2*)(regp2 + (size_t)blockIdx.x*512 + ch) = o2;
}

// ---------------- head: reg from k_ln partials; dec0 from fp32 decf; gate+expert select ----------------
__global__ __launch_bounds__(512) void k_head(
    const float* __restrict__ decf,
    const float* __restrict__ regp2,
    const float* __restrict__ gumbel, const float* __restrict__ gate_w,
    const float* __restrict__ gate_b, const float* __restrict__ actor_w,
    const float* __restrict__ actor_b, const float* __restrict__ critic_w,
    const float* __restrict__ critic_b, float* __restrict__ out, int bofs)
{
    __shared__ float sred[8][4];
    __shared__ float sg;
    __shared__ int sestar;
    int bl = blockIdx.x, tid = threadIdx.x;      // tid = channel
    int b = bofs + bl;
    const float* rp = regp2 + (size_t)bl*32*512; // 32 partial blocks per batch (128 rows / 4)
    float r0 = 0.0f;
    #pragma unroll
    for (int p = 0; p < 32; ++p) r0 += rp[p*512 + tid];
    r0 *= (1.0f/LL);
    float dec0 = decf[(size_t)bl*512 + tid];

    int lane = tid & 63, wid = tid >> 6;
    float p[4];
    #pragma unroll
    for (int e = 0; e < 4; ++e) p[e] = r0 * gate_w[tid*4 + e];
    #pragma unroll
    for (int e = 0; e < 4; ++e) {
        float v = p[e];
        for (int off = 32; off; off >>= 1) v += __shfl_down(v, off);
        p[e] = v;
    }
    if (!lane) { for (int e = 0; e < 4; ++e) sred[wid][e] = p[e]; }
    __syncthreads();
    if (!tid) {
        float ge[4]; float mx = -1e30f;
        for (int e = 0; e < 4; ++e) {
            float acc = gate_b[e] + gumbel[b*4 + e];
            for (int w = 0; w < 8; ++w) acc += sred[w][e];
            ge[e] = acc;
            if (acc > mx) mx = acc;
        }
        float ys[4], den = 0.f;
        for (int e = 0; e < 4; ++e) { ys[e] = expf(ge[e] - mx); den += ys[e]; }
        int estar = 0; float best = ge[0];
        for (int e = 1; e < 4; ++e) if (ge[e] > best) { best = ge[e]; estar = e; }
        float ye = ys[estar] / den;
        float gv = (1.0f + ye) - ye;             // exactly as reference
        for (int e = 0; e < 4; ++e) out[2048 + b*4 + e] = (e == estar) ? gv : 0.0f;
        sg = gv; sestar = estar;
    }
    __syncthreads();
    float gv = sg; int estar = sestar;
    const float* aw  = actor_w  + (size_t)estar * HD * 3;
    const float* cwp = critic_w + (size_t)estar * HD;
    float q[4];
    #pragma unroll
    for (int a = 0; a < 3; ++a) q[a] = dec0 * aw[tid*3 + a];
    q[3] = dec0 * cwp[tid];
    #pragma unroll
    for (int e = 0; e < 4; ++e) {
        float v = q[e];
        for (int off = 32; off; off >>= 1) v += __shfl_down(v, off);
        q[e] = v;
    }
    __syncthreads();
    if (!lane) { for (int e = 0; e < 4; ++e) sred[wid][e] = q[e]; }
    __syncthreads();
    if (!tid) {
        for (int a = 0; a < 3; ++a) {
            float acc = actor_b[estar*3 + a];
            for (int w = 0; w < 8; ++w) acc += sred[w][a];
            out[b*3 + a] = gv * acc;
        }
        float acc = critic_b[estar];
        for (int w = 0; w < 8; ++w) acc += sred[w][3];
        out[1536 + b] = gv * acc;
    }
}

extern "C" void kernel_launch(void* const* d_in, const int* in_sizes, int n_in,
                              void* d_out, int out_size, void* d_ws, size_t ws_size,
                              hipStream_t stream)
{
    const float* x        = (const float*)d_in[0];
    const float* gumbel   = (const float*)d_in[1];
    const float* w0       = (const float*)d_in[2];
    const float* b0       = (const float*)d_in[3];
    const float* ln_g     = (const float*)d_in[4];
    const float* ln_b     = (const float*)d_in[5];
    const float* gate_w   = (const float*)d_in[6];
    const float* gate_b   = (const float*)d_in[7];
    const float* actor_w  = (const float*)d_in[8];
    const float* actor_b  = (const float*)d_in[9];
    const float* critic_w = (const float*)d_in[10];
    const float* critic_b = (const float*)d_in[11];
    const float* in_w[2]   = {(const float*)d_in[12], (const float*)d_in[22]};
    const float* in_b[2]   = {(const float*)d_in[13], (const float*)d_in[23]};
    const float* conv_w[2] = {(const float*)d_in[14], (const float*)d_in[24]};
    const float* conv_b[2] = {(const float*)d_in[15], (const float*)d_in[25]};
    const float* xp_w[2]   = {(const float*)d_in[16], (const float*)d_in[26]};
    const float* xp_b[2]   = {(const float*)d_in[17], (const float*)d_in[27]};
    const float* dt_w[2]   = {(const float*)d_in[18], (const float*)d_in[28]};
    const float* dt_b[2]   = {(const float*)d_in[19], (const float*)d_in[29]};
    const float* out_w[2]  = {(const float*)d_in[20], (const float*)d_in[30]};
    const float* out_b[2]  = {(const float*)d_in[21], (const float*)d_in[31]};

    // Per-row scratch: union(xb fp32 | xchi)(2048) + hhi(1024) + Abig hi(2048) = 5120 B
    int CB = 512;
    while (CB > 1 && (size_t)CB * LL * 5120 + (16u << 20) > ws_size) CB >>= 1;
    const int rows = CB * LL;
    const size_t CSZ = (size_t)rows * HD;        // elements per 512-wide buffer

    char* p = (char*)d_ws;
    float* xb = (float*)p;                       // union with xchi (phases don't overlap)
    unsigned short* xchi = (unsigned short*)p;   p += CSZ * 4;
    unsigned short* hhi = (unsigned short*)p;    p += CSZ * 2;
    unsigned short* Abig_hi = (unsigned short*)p; p += CSZ * 2 * 2;  // rows x 1024 bf16
    unsigned short* wtb = (unsigned short*)p;  p += (size_t)4 * 524288 * 2;  // hi-only weights
    unsigned short* iwh[2] = {wtb,            wtb + 2*524288};
    unsigned short* owh[2] = {wtb +  524288,  wtb + 3*524288};
    unsigned short* Uhi[2] = {(unsigned short*)p, (unsigned short*)p + 262144}; p += 262144u * 2 * 2;
    float* biasU[2] = {(float*)p, (float*)p + 512};           p += 1024 * 4;
    float* decf = (float*)p;                     p += (size_t)(rows/LL) * 512 * 4;  // fp32 decision rows
    // regp2: (rows/4) x 512 fp32 — OVERLAYS Abig_hi (dead after MODE1; k_ln writes it after
    // MODE1 reads Abig; m=1's write is the one k_head consumes; all kernels serial on stream).
    float* regp2 = (float*)Abig_hi;

    // weight transforms: 3 launches (hi-only outputs)
    k_cvt2<<<4096, 256, 0, stream>>>(in_w[0], in_w[1], iwh[0], iwh[1], 1024, 9);
    k_cvt2<<<4096, 256, 0, stream>>>(out_w[0], out_w[1], owh[0], owh[1], 512, 10);
    k_mkU2<<<2052, 256, 0, stream>>>(xp_w[0], dt_w[0], xp_b[0], dt_b[0],
                                     xp_w[1], dt_w[1], xp_b[1], dt_b[1],
                                     Uhi[0], Uhi[1], biasU[0], biasU[1]);

    const int nchunk = BB / CB;
    for (int c = 0; c < nchunk; ++c) {
        const float* xin = x + (size_t)c * CB * LL * FD;
        k_embed<<<rows*HD/256, 256, 0, stream>>>(xin, w0, b0, hhi);
        for (int m = 0; m < 2; ++m) {
            // in_proj + fused conv: A=hhi; z->Abig[:,512:], conv(xi)->xc
            k_mgemm<512, 0><<<dim3(rows/128, 8), 512, 0, stream>>>(
                hhi, iwh[m], in_b[m], conv_w[m], conv_b[m],
                nullptr,
                nullptr, Abig_hi, xchi);
            // dt GEMM: A=xc; out = xc * softplus(xc@U + biasU) -> Abig[:,0:512]
            k_mgemm<512, 2><<<dim3(rows/128, 4), 512, 0, stream>>>(
                xchi, Uhi[m], biasU[m], nullptr, nullptr,
                nullptr,
                nullptr, Abig_hi, nullptr);
            // out_proj: A=Abig; out = Abig@out_w + out_b + resid(hhi) -> xb fp32
            k_mgemm<1024, 1><<<dim3(rows/128, 4), 512, 0, stream>>>(
                Abig_hi, owh[m], out_b[m], nullptr, nullptr,
                hhi,
                xb, nullptr, nullptr);
            // LN(xb) -> hhi + per-4-row channel partials + fp32 decision rows
            k_ln<<<rows/4, 256, 0, stream>>>(xb, ln_g, ln_b, hhi, regp2, decf);
        }
        k_head<<<CB, 512, 0, stream>>>(decf, regp2, gumbel, gate_w, gate_b,
                                       actor_w, actor_b, critic_w, critic_b,
                                       (float*)d_out, c*CB);
    }
}

// Round 18
// 1048.528 us; speedup vs baseline: 1.4093x; 1.0214x over previous
//
#include <hip/hip_runtime.h>
#include <math.h>

#define BB 512
#define LL 128
#define FD 8
#define HD 512
#define EPSV 1e-5f

typedef __attribute__((ext_vector_type(8))) __bf16 bf16x8;
typedef __attribute__((ext_vector_type(4))) float floatx4;
typedef __attribute__((ext_vector_type(8))) unsigned short us8;

// Round-31 == round-30 resubmitted verbatim (round-30's bench died at container acquisition —
// the same transient infra error as rounds 11/12, where an identical-source retry succeeded).
// Hardware-exp activations: v_exp_f32 (__expf) rel err ~1e-6 — 4 orders below the output
// path's bf16 quantum (absmax pinned at 0.015625 across three precision cuts).
// k_head's gate expf stays libm-exact (feeds softmax/argmax selection).
__device__ __forceinline__ float silu_f(float x){ return x / (1.0f + __expf(-x)); }
__device__ __forceinline__ float softplus_f(float x){ return (x > 20.0f) ? x : log1pf(__expf(x)); }

__device__ __forceinline__ unsigned short f2bf(float x){
    union { float f; unsigned u; } v; v.f = x;
    unsigned r = v.u + 0x7fffu + ((v.u >> 16) & 1u);   // RNE
    return (unsigned short)(r >> 16);
}
__device__ __forceinline__ float bf2f(unsigned short h){
    union { unsigned u; float f; } v; v.u = ((unsigned)h) << 16; return v.f;
}

// ---------------- embed: h = x @ w0 + b0 -> bf16 ----------------
__global__ __launch_bounds__(256) void k_embed(const float* __restrict__ x,
    const float* __restrict__ w0, const float* __restrict__ b0,
    unsigned short* __restrict__ hhi)
{
    int idx = blockIdx.x*256 + threadIdx.x;      // over rows*HD
    int c = idx & (HD-1);
    int row = idx >> 9;
    const float* xr = x + (size_t)row*FD;
    float acc = b0[c];
    #pragma unroll
    for (int f=0; f<FD; ++f) acc = fmaf(xr[f], w0[f*HD + c], acc);
    hhi[idx] = f2bf(acc);
}

// ---------------- weight transpose for BOTH layers: W[K][N] -> Wt[N][K] bf16 ----------------
__global__ __launch_bounds__(256) void k_cvt2(const float* __restrict__ W0,
    const float* __restrict__ W1,
    unsigned short* __restrict__ Th0, unsigned short* __restrict__ Th1,
    int N, int kbits)
{
    int total = N << kbits;
    int idx = blockIdx.x*256 + threadIdx.x;
    const float* W = W0; unsigned short* Th = Th0;
    if (idx >= total) { idx -= total; W = W1; Th = Th1; }
    int K = 1 << kbits;
    int n = idx >> kbits, k = idx & (K-1);
    Th[idx] = f2bf(W[(size_t)k*N + n]);
}

// ---------------- U = xp_w @ dt_w (512x512, B-layout [n][c]) + biasU, both layers ----------------
__global__ __launch_bounds__(256) void k_mkU2(
    const float* __restrict__ xw0, const float* __restrict__ dw0,
    const float* __restrict__ xpb0, const float* __restrict__ dtb0,
    const float* __restrict__ xw1, const float* __restrict__ dw1,
    const float* __restrict__ xpb1, const float* __restrict__ dtb1,
    unsigned short* __restrict__ Uhi0, unsigned short* __restrict__ Uhi1,
    float* __restrict__ bU0, float* __restrict__ bU1)
{
    int blk = blockIdx.x, tid = threadIdx.x;
    if (blk < 2048) {
        int layer = blk >> 10;
        const float* xw = layer ? xw1 : xw0;
        const float* dw = layer ? dw1 : dw0;
        unsigned short* Uh = layer ? Uhi1 : Uhi0;
        int idx = (blk & 1023)*256 + tid;        // n*512 + c, c fastest
        int n = idx >> 9, c = idx & 511;
        float acc = 0.0f;
        #pragma unroll
        for (int j = 0; j < 16; ++j) acc = fmaf(xw[c*16 + j], dw[j*512 + n], acc);
        Uh[idx] = f2bf(acc);
    } else {
        int q = blk - 2048;                      // 0..3
        int layer = q >> 1;
        const float* xpb = layer ? xpb1 : xpb0;
        const float* dw  = layer ? dw1  : dw0;
        const float* dtb = layer ? dtb1 : dtb0;
        float* bU = layer ? bU1 : bU0;
        int n = (q & 1)*256 + tid;
        float acc = dtb[n];
        #pragma unroll
        for (int j = 0; j < 16; ++j) acc = fmaf(xpb[j], dw[j*512 + n], acc);
        bU[n] = acc;
    }
}

// ---------------- bf16 x bf16 MFMA GEMM, 128x128 tile, 8 waves, 16x16x32, BK=64 ----------------
// Structure == round-29 (1071us best). Only change vs that anchor: __expf in the epilogue
// activations (VALU was the top pipe at 43.5% — epilogue transcendentals are the VALU tail).
// K-loop/grid/swizzle: M-fast grid (A-tile reuse pinned to one XCD's L2), XOR chunk swizzle.
// MODE 0 (in_proj, K=512, N=1024): A=hhi.
//    nBase<512  (z):  silu -> Abig[row][512+col] bf16
//    nBase>=512 (xi): fused conv3+silu -> xc[row][col-512] bf16
// MODE 1 (out_proj, K=1024, N=512): A=Abig; outF = v + bias + resid(bf16) fp32
// MODE 2 (dt, K=512, N=512): A=xc; out = xc * softplus(v + biasU) -> Abig[row][col]
template<int KDIM, int MODE>
__global__ __launch_bounds__(512, 4) void k_mgemm(
    const unsigned short* __restrict__ Ahi,
    const unsigned short* __restrict__ Bhi,
    const float* __restrict__ bias,
    const float* __restrict__ cw, const float* __restrict__ cb,
    const unsigned short* __restrict__ rhi,
    float* __restrict__ outF,
    unsigned short* __restrict__ oAhi,
    unsigned short* __restrict__ xchi)
{
    // LDS (ushort elems): A [0,8192) | Bhi [8192,16384) = 32768 B staging.
    // Epilogue reuses the buffer as sc[128][65] fp32 = 33280 B -> smem = 33280.
    __shared__ __align__(16) char smem[33280];
    unsigned short* lds = (unsigned short*)smem;
    const int tid  = threadIdx.x;
    const int wv   = tid >> 6, lane = tid & 63;
    const int quad = lane >> 4, l16 = lane & 15;
    const size_t mBase = (size_t)blockIdx.x * 128;   // M fast — M-tile m pins to XCD m%8
    const int nBase = blockIdx.y * 128;
    const int wm = (wv & 3) * 32, wn = (wv >> 2) * 64;

    floatx4 acc[2][4] = {};

    const int rowIn = lane >> 2;                 // 0..15
    const int kofs  = ((lane & 3) ^ ((lane >> 3) & 3)) * 8;  // swizzled source k-chunk
    const int qx    = (quad ^ ((l16 >> 1) & 3)) * 8;         // swizzled read k-chunk
    const unsigned short* gsrc[2];
    gsrc[0] = Ahi + mBase * KDIM;
    gsrc[1] = Bhi + (size_t)nBase * KDIM;

    for (int k0 = 0; k0 < KDIM; k0 += 64) {
        // stage 2 operand tiles x 2 k-sub-tiles; 4 global_load_lds per thread
        #pragma unroll
        for (int b = 0; b < 2; ++b) {
            #pragma unroll
            for (int s = 0; s < 2; ++s) {
                int row = wv * 16 + rowIn;
                const unsigned short* g = gsrc[b] + (size_t)row * KDIM + k0 + s*32 + kofs;
                unsigned short* l = &lds[b * 8192 + s * 4096 + wv * 512]; // +lane*16B implicit
                __builtin_amdgcn_global_load_lds(
                    (const __attribute__((address_space(1))) void*)g,
                    (__attribute__((address_space(3))) void*)l, 16, 0, 0);
            }
        }
        __syncthreads();
        #pragma unroll
        for (int s = 0; s < 2; ++s) {
            const int kb = s * 4096;
            bf16x8 ah[2];
            #pragma unroll
            for (int i = 0; i < 2; ++i) {
                int am = wm + 16*i + l16;
                ah[i] = *(const bf16x8*)&lds[kb + am*32 + qx];
            }
            #pragma unroll
            for (int j = 0; j < 4; ++j) {
                int bn = wn + 16*j + l16;
                bf16x8 bh = *(const bf16x8*)&lds[8192 + kb + bn*32 + qx];
                #pragma unroll
                for (int i = 0; i < 2; ++i)
                    acc[i][j] = __builtin_amdgcn_mfma_f32_16x16x32_bf16(ah[i], bh, acc[i][j], 0, 0, 0);
            }
        }
        __syncthreads();
    }

    // ---- unified coalesced epilogue: two 64-col halves through LDS (stride 65) ----
    float* sc = (float*)smem;
    const int q8 = (tid & 7) * 8;                // col chunk within half
    const int rg = tid >> 3;                     // 0..63 row group
    #pragma unroll
    for (int half = 0; half < 2; ++half) {
        __syncthreads();
        if ((wv >> 2) == half) {                 // 4 waves owning this half stage v+bias
            #pragma unroll
            for (int i = 0; i < 2; ++i)
                #pragma unroll
                for (int r = 0; r < 4; ++r) {
                    int rl = wm + 16*i + quad*4 + r;
                    #pragma unroll
                    for (int j = 0; j < 4; ++j) {
                        int cl = 16*j + l16;
                        sc[rl*65 + cl] = acc[i][j][r] + bias[nBase + half*64 + cl];
                    }
                }
        }
        __syncthreads();
        #pragma unroll
        for (int pss = 0; pss < 2; ++pss) {
            int l = pss*64 + rg;                 // row within 128-row tile
            size_t grow = mBase + l;
            if (MODE == 0) {
                if (nBase < 512) {               // z half: silu -> Abig[:,512+col]
                    int gcol = nBase + half*64 + q8;
                    us8 hh;
                    #pragma unroll
                    for (int k = 0; k < 8; ++k)
                        hh[k] = f2bf(silu_f(sc[l*65 + q8 + k]));
                    *(us8*)(oAhi + grow*1024 + 512 + gcol) = hh;
                } else {                         // xi half: conv3+silu -> xc
                    int gcol = (nBase - 512) + half*64 + q8;
                    us8 hh;
                    #pragma unroll
                    for (int k = 0; k < 8; ++k) {
                        int cc = q8 + k;
                        float xm = (l > 0)   ? sc[(l-1)*65 + cc] : 0.0f;
                        float x0 = sc[l*65 + cc];
                        float xp = (l < 127) ? sc[(l+1)*65 + cc] : 0.0f;
                        int gc = gcol + k;
                        float v = cb[gc];
                        v = fmaf(xm, cw[gc*3+0], v);
                        v = fmaf(x0, cw[gc*3+1], v);
                        v = fmaf(xp, cw[gc*3+2], v);
                        hh[k] = f2bf(silu_f(v));
                    }
                    *(us8*)(xchi + grow*512 + gcol) = hh;
                }
            } else if (MODE == 1) {              // fp32 out = (v+bias) + resid(bf16), float4 x2
                int gcol = nBase + half*64 + q8;
                us8 rh = *(const us8*)(rhi + grow*512 + gcol);
                float o[8];
                #pragma unroll
                for (int k = 0; k < 8; ++k)
                    o[k] = sc[l*65 + q8 + k] + bf2f(rh[k]);
                float4 o0, o1;
                o0.x=o[0]; o0.y=o[1]; o0.z=o[2]; o0.w=o[3];
                o1.x=o[4]; o1.y=o[5]; o1.z=o[6]; o1.w=o[7];
                *(float4*)(outF + grow*512 + gcol)     = o0;
                *(float4*)(outF + grow*512 + gcol + 4) = o1;
            } else {                             // MODE 2: xid = xc*softplus(v)
                int gcol = nBase + half*64 + q8;
                us8 xh = *(const us8*)(Ahi + grow*512 + gcol);
                us8 hh;
                #pragma unroll
                for (int k = 0; k < 8; ++k) {
                    float o = bf2f(xh[k]) * softplus_f(sc[l*65 + q8 + k]);
                    hh[k] = f2bf(o);
                }
                *(us8*)(oAhi + grow*1024 + gcol) = hh;
            }
        }
    }
}

// ---------------- layernorm of pre-summed row; emit bf16 + partials + fp32 decision row ----
__global__ __launch_bounds__(256) void k_ln(const float* __restrict__ in,
    const float* __restrict__ g, const float* __restrict__ b,
    unsigned short* ohi, float* __restrict__ regp2, float* __restrict__ decf)
{
    __shared__ float sacc[4][512];
    int wv = threadIdx.x >> 6, lane = threadIdx.x & 63;
    size_t row = (size_t)blockIdx.x * 4 + wv;
    size_t base = row*512 + lane*8;
    float4 v0 = *(const float4*)(in + base);
    float4 v1 = *(const float4*)(in + base + 4);
    float vals[8] = {v0.x,v0.y,v0.z,v0.w,v1.x,v1.y,v1.z,v1.w};
    float s = 0.f, q = 0.f;
    #pragma unroll
    for (int k = 0; k < 8; ++k) { s += vals[k]; q += vals[k]*vals[k]; }
    #pragma unroll
    for (int off = 32; off; off >>= 1) { s += __shfl_xor(s, off); q += __shfl_xor(q, off); }
    float mu = s * (1.0f/512.0f);
    float rs = rsqrtf(q*(1.0f/512.0f) - mu*mu + EPSV);
    const float* gp = g + lane*8;
    const float* bp = b + lane*8;
    float4 g0 = *(const float4*)gp, g1 = *(const float4*)(gp+4);
    float4 b0 = *(const float4*)bp, b1 = *(const float4*)(bp+4);
    float gs[8] = {g0.x,g0.y,g0.z,g0.w,g1.x,g1.y,g1.z,g1.w};
    float bs[8] = {b0.x,b0.y,b0.z,b0.w,b1.x,b1.y,b1.z,b1.w};
    us8 hh;
    float ov[8];
    #pragma unroll
    for (int k = 0; k < 8; ++k) {
        float o = (vals[k] - mu) * rs * gs[k] + bs[k];
        ov[k] = o;
        sacc[wv][lane*8 + k] = o;
        hh[k] = f2bf(o);
    }
    *(us8*)(ohi + base) = hh;
    if (wv == 3 && (blockIdx.x & 31) == 31) {    // last row of this 128-row batch: fp32 decision row
        size_t batch = row >> 7;
        float4 d0, d1;
        d0.x=ov[0]; d0.y=ov[1]; d0.z=ov[2]; d0.w=ov[3];
        d1.x=ov[4]; d1.y=ov[5]; d1.z=ov[6]; d1.w=ov[7];
        *(float4*)(decf + batch*512 + lane*8)     = d0;
        *(float4*)(decf + batch*512 + lane*8 + 4) = d1;
    }
    __syncthreads();
    int ch = threadIdx.x * 2;
    float s0 = (sacc[0][ch]   + sacc[1][ch])   + (sacc[2][ch]   + sacc[3][ch]);
    float s1 = (sacc[0][ch+1] + sacc[1][ch+1]) + (sacc[2][ch+1] + sacc[3][ch+1]);
    float2 o2; o2.x = s0; o2.y = s1;
    *(float2*)(regp2 + (size_t)blockIdx.x*512 + ch) = o2;
}

// ---------------- head: reg from k_ln partials; dec0 from fp32 decf; gate+expert select ----------------
__global__ __launch_bounds__(512) void k_head(
    const float* __restrict__ decf,
    const float* __restrict__ regp2,
    const float* __restrict__ gumbel, const float* __restrict__ gate_w,
    const float* __restrict__ gate_b, const float* __restrict__ actor_w,
    const float* __restrict__ actor_b, const float* __restrict__ critic_w,
    const float* __restrict__ critic_b, float* __restrict__ out, int bofs)
{
    __shared__ float sred[8][4];
    __shared__ float sg;
    __shared__ int sestar;
    int bl = blockIdx.x, tid = threadIdx.x;      // tid = channel
    int b = bofs + bl;
    const float* rp = regp2 + (size_t)bl*32*512; // 32 partial blocks per batch (128 rows / 4)
    float r0 = 0.0f;
    #pragma unroll
    for (int p = 0; p < 32; ++p) r0 += rp[p*512 + tid];
    r0 *= (1.0f/LL);
    float dec0 = decf[(size_t)bl*512 + tid];

    int lane = tid & 63, wid = tid >> 6;
    float p[4];
    #pragma unroll
    for (int e = 0; e < 4; ++e) p[e] = r0 * gate_w[tid*4 + e];
    #pragma unroll
    for (int e = 0; e < 4; ++e) {
        float v = p[e];
        for (int off = 32; off; off >>= 1) v += __shfl_down(v, off);
        p[e] = v;
    }
    if (!lane) { for (int e = 0; e < 4; ++e) sred[wid][e] = p[e]; }
    __syncthreads();
    if (!tid) {
        float ge[4]; float mx = -1e30f;
        for (int e = 0; e < 4; ++e) {
            float acc = gate_b[e] + gumbel[b*4 + e];
            for (int w = 0; w < 8; ++w) acc += sred[w][e];
            ge[e] = acc;
            if (acc > mx) mx = acc;
        }
        float ys[4], den = 0.f;
        for (int e = 0; e < 4; ++e) { ys[e] = expf(ge[e] - mx); den += ys[e]; }
        int estar = 0; float best = ge[0];
        for (int e = 1; e < 4; ++e) if (ge[e] > best) { best = ge[e]; estar = e; }
        float ye = ys[estar] / den;
        float gv = (1.0f + ye) - ye;             // exactly as reference
        for (int e = 0; e < 4; ++e) out[2048 + b*4 + e] = (e == estar) ? gv : 0.0f;
        sg = gv; sestar = estar;
    }
    __syncthreads();
    float gv = sg; int estar = sestar;
    const float* aw  = actor_w  + (size_t)estar * HD * 3;
    const float* cwp = critic_w + (size_t)estar * HD;
    float q[4];
    #pragma unroll
    for (int a = 0; a < 3; ++a) q[a] = dec0 * aw[tid*3 + a];
    q[3] = dec0 * cwp[tid];
    #pragma unroll
    for (int e = 0; e < 4; ++e) {
        float v = q[e];
        for (int off = 32; off; off >>= 1) v += __shfl_down(v, off);
        q[e] = v;
    }
    __syncthreads();
    if (!lane) { for (int e = 0; e < 4; ++e) sred[wid][e] = q[e]; }
    __syncthreads();
    if (!tid) {
        for (int a = 0; a < 3; ++a) {
            float acc = actor_b[estar*3 + a];
            for (int w = 0; w < 8; ++w) acc += sred[w][a];
            out[b*3 + a] = gv * acc;
        }
        float acc = critic_b[estar];
        for (int w = 0; w < 8; ++w) acc += sred[w][3];
        out[1536 + b] = gv * acc;
    }
}

extern "C" void kernel_launch(void* const* d_in, const int* in_sizes, int n_in,
                              void* d_out, int out_size, void* d_ws, size_t ws_size,
                              hipStream_t stream)
{
    const float* x        = (const float*)d_in[0];
    const float* gumbel   = (const float*)d_in[1];
    const float* w0       = (const float*)d_in[2];
    const float* b0       = (const float*)d_in[3];
    const float* ln_g     = (const float*)d_in[4];
    const float* ln_b     = (const float*)d_in[5];
    const float* gate_w   = (const float*)d_in[6];
    const float* gate_b   = (const float*)d_in[7];
    const float* actor_w  = (const float*)d_in[8];
    const float* actor_b  = (const float*)d_in[9];
    const float* critic_w = (const float*)d_in[10];
    const float* critic_b = (const float*)d_in[11];
    const float* in_w[2]   = {(const float*)d_in[12], (const float*)d_in[22]};
    const float* in_b[2]   = {(const float*)d_in[13], (const float*)d_in[23]};
    const float* conv_w[2] = {(const float*)d_in[14], (const float*)d_in[24]};
    const float* conv_b[2] = {(const float*)d_in[15], (const float*)d_in[25]};
    const float* xp_w[2]   = {(const float*)d_in[16], (const float*)d_in[26]};
    const float* xp_b[2]   = {(const float*)d_in[17], (const float*)d_in[27]};
    const float* dt_w[2]   = {(const float*)d_in[18], (const float*)d_in[28]};
    const float* dt_b[2]   = {(const float*)d_in[19], (const float*)d_in[29]};
    const float* out_w[2]  = {(const float*)d_in[20], (const float*)d_in[30]};
    const float* out_b[2]  = {(const float*)d_in[21], (const float*)d_in[31]};

    // Per-row scratch: union(xb fp32 | xchi)(2048) + hhi(1024) + Abig hi(2048) = 5120 B
    int CB = 512;
    while (CB > 1 && (size_t)CB * LL * 5120 + (16u << 20) > ws_size) CB >>= 1;
    const int rows = CB * LL;
    const size_t CSZ = (size_t)rows * HD;        // elements per 512-wide buffer

    char* p = (char*)d_ws;
    float* xb = (float*)p;                       // union with xchi (phases don't overlap)
    unsigned short* xchi = (unsigned short*)p;   p += CSZ * 4;
    unsigned short* hhi = (unsigned short*)p;    p += CSZ * 2;
    unsigned short* Abig_hi = (unsigned short*)p; p += CSZ * 2 * 2;  // rows x 1024 bf16
    unsigned short* wtb = (unsigned short*)p;  p += (size_t)4 * 524288 * 2;  // hi-only weights
    unsigned short* iwh[2] = {wtb,            wtb + 2*524288};
    unsigned short* owh[2] = {wtb +  524288,  wtb + 3*524288};
    unsigned short* Uhi[2] = {(unsigned short*)p, (unsigned short*)p + 262144}; p += 262144u * 2 * 2;
    float* biasU[2] = {(float*)p, (float*)p + 512};           p += 1024 * 4;
    float* decf = (float*)p;                     p += (size_t)(rows/LL) * 512 * 4;  // fp32 decision rows
    // regp2: (rows/4) x 512 fp32 — OVERLAYS Abig_hi (dead after MODE1; k_ln writes it after
    // MODE1 reads Abig; m=1's write is the one k_head consumes; all kernels serial on stream).
    float* regp2 = (float*)Abig_hi;

    // weight transforms: 3 launches
    k_cvt2<<<4096, 256, 0, stream>>>(in_w[0], in_w[1], iwh[0], iwh[1], 1024, 9);
    k_cvt2<<<4096, 256, 0, stream>>>(out_w[0], out_w[1], owh[0], owh[1], 512, 10);
    k_mkU2<<<2052, 256, 0, stream>>>(xp_w[0], dt_w[0], xp_b[0], dt_b[0],
                                     xp_w[1], dt_w[1], xp_b[1], dt_b[1],
                                     Uhi[0], Uhi[1], biasU[0], biasU[1]);

    const int nchunk = BB / CB;
    for (int c = 0; c < nchunk; ++c) {
        const float* xin = x + (size_t)c * CB * LL * FD;
        k_embed<<<rows*HD/256, 256, 0, stream>>>(xin, w0, b0, hhi);
        for (int m = 0; m < 2; ++m) {
            // in_proj + fused conv: A=hhi; z->Abig[:,512:], conv(xi)->xc
            k_mgemm<512, 0><<<dim3(rows/128, 8), 512, 0, stream>>>(
                hhi, iwh[m], in_b[m], conv_w[m], conv_b[m],
                nullptr,
                nullptr, Abig_hi, xchi);
            // dt GEMM: A=xc; out = xc * softplus(xc@U + biasU) -> Abig[:,0:512]
            k_mgemm<512, 2><<<dim3(rows/128, 4), 512, 0, stream>>>(
                xchi, Uhi[m], biasU[m], nullptr, nullptr,
                nullptr,
                nullptr, Abig_hi, nullptr);
            // out_proj: A=Abig; out = Abig@out_w + out_b + resid(hhi) -> xb fp32
            k_mgemm<1024, 1><<<dim3(rows/128, 4), 512, 0, stream>>>(
                Abig_hi, owh[m], out_b[m], nullptr, nullptr,
                hhi,
                xb, nullptr, nullptr);
            // LN(xb) -> hhi + per-4-row channel partials + fp32 decision rows
            k_ln<<<rows/4, 256, 0, stream>>>(xb, ln_g, ln_b, hhi, regp2, decf);
        }
        k_head<<<CB, 512, 0, stream>>>(decf, regp2, gumbel, gate_w, gate_b,
                                       actor_w, actor_b, critic_w, critic_b,
                                       (float*)d_out, c*CB);
    }
}